// Round 3
// baseline (465.641 us; speedup 1.0000x reference)
//
#include <hip/hip_runtime.h>

#define NTOK 1024
#define NB   64
#define CD   256
#define NHEAD 8
#define HDIM 32
#define NS 256
#define NBC 16384

typedef __attribute__((ext_vector_type(8))) short short8v;
typedef __attribute__((ext_vector_type(4))) short short4v;
typedef __attribute__((ext_vector_type(4))) float f32x4;

// round-to-nearest-even fp32 -> bf16 (low 16 bits returned)
__device__ __forceinline__ unsigned bfr(float x){
  unsigned u = __float_as_uint(x);
  return (u + 0x7fffu + ((u>>16)&1u)) >> 16;
}
// two-term split: x ~= hi + lo, both bf16
__device__ __forceinline__ void split2(float x, short &h, short &l){
  unsigned hu = bfr(x);
  float hf = __uint_as_float(hu << 16);
  unsigned lu = bfr(x - hf);
  h = (short)hu; l = (short)lu;
}

// async global->LDS, 16 bytes per lane; LDS dest = wave-uniform base + lane*16
__device__ __forceinline__ void gl16(const void* g, void* l){
  __builtin_amdgcn_global_load_lds((__attribute__((address_space(1))) void*)g,
                                   (__attribute__((address_space(3))) void*)l, 16, 0, 0);
}

// ---- weights -> bf16 hi/lo planes (row-major [n][k]) ----
__global__ __launch_bounds__(256) void k_wcvt(const float* __restrict__ ipw, const float* __restrict__ ow,
                                              const float* __restrict__ srw,
                                              short* __restrict__ Wih, short* __restrict__ Wil,
                                              short* __restrict__ Woh, short* __restrict__ Wol,
                                              short* __restrict__ Wsh, short* __restrict__ Wsl){
  int u = blockIdx.x*256 + threadIdx.x;   // 65536 units of 8 elements
  float xs[8];
  short* dh; short* dl; int dof;
  if (u < 24576){
    int n = u >> 5, off = (u & 31)*8;
    const float* s = ipw + n*CD + off;
    #pragma unroll
    for (int i=0;i<8;++i) xs[i] = s[i];
    dh = Wih; dl = Wil; dof = n*CD + off;
  } else if (u < 32768){
    int v = u - 24576;
    int n = v >> 5, off = (v & 31)*8;
    const float* s = ow + n*CD + off;
    #pragma unroll
    for (int i=0;i<8;++i) xs[i] = s[i];
    dh = Woh; dl = Wol; dof = n*CD + off;
  } else {
    int v = u - 32768;
    int n = v >> 7, koff = (v & 127)*8;
    int g = koff >> 8, cin0 = koff & 255;
    #pragma unroll
    for (int i=0;i<8;++i) xs[i] = srw[n*1024 + (cin0+i)*4 + g];
    dh = Wsh; dl = Wsl; dof = n*1024 + koff;
  }
  short8v h, l;
  #pragma unroll
  for (int i=0;i<8;++i){ short a,b; split2(xs[i],a,b); h[i]=a; l[i]=b; }
  *(short8v*)(dh + dof) = h;
  *(short8v*)(dl + dof) = l;
}

// ---- query -> bf16 hi/lo planes, rows m = b*1024 + ntok ----
__global__ __launch_bounds__(256) void k_qcvt(const float* __restrict__ q, short* __restrict__ Qh,
                                              short* __restrict__ Ql){
  int idx = blockIdx.x*256 + threadIdx.x;      // 2,097,152 units of 8
  int m = idx >> 5;
  int off = (idx & 31)*8;
  const float* src = q + (m & 1023)*NBC + (m >> 10)*CD + off;
  float4 a = *(const float4*)src;
  float4 b4 = *(const float4*)(src+4);
  float xs[8] = {a.x,a.y,a.z,a.w,b4.x,b4.y,b4.z,b4.w};
  short8v h, l;
  #pragma unroll
  for (int i=0;i<8;++i){ short hh,ll; split2(xs[i],hh,ll); h[i]=hh; l[i]=ll; }
  *(short8v*)(Qh + m*CD + off) = h;
  *(short8v*)(Ql + m*CD + off) = l;
}

// ---- trig tables ----
__global__ __launch_bounds__(256) void k_trig(float* __restrict__ t1, float* __restrict__ t2){
  int n = blockIdx.x*256 + threadIdx.x;
  const float c = 1.57079632679489662f;
  float aa = c * (float)(n >> 5) / 32.0f;
  float bb = c * (float)(n & 31) / 32.0f;
  t1[n*4+0]=cosf(aa); t1[n*4+1]=sinf(aa); t1[n*4+2]=cosf(bb); t1[n*4+3]=sinf(bb);
  if (n < 256){
    float a2 = c * (float)(n >> 4) / 16.0f;
    float b2 = c * (float)(n & 15) / 16.0f;
    t2[n*4+0]=cosf(a2); t2[n*4+1]=sinf(a2); t2[n*4+2]=cosf(b2); t2[n*4+3]=sinf(b2);
  }
}

// ---- SE: partial mean, read from bf16 hi+lo planes (67MB instead of 268MB fp32) ----
__global__ __launch_bounds__(256) void k_semean(const short* __restrict__ Qh, const short* __restrict__ Ql,
                                                float* __restrict__ part){
  __shared__ float red[8][256];
  int b = blockIdx.x >> 2, qr = blockIdx.x & 3;
  int t = threadIdx.x;
  int c8 = (t & 31)*8;            // column group (8 cols)
  int ng = t >> 5;                // n-slice 0..7 (32 rows each)
  size_t base = ((size_t)(b*1024 + qr*256 + ng*32))*CD + c8;
  float s[8] = {0.f,0.f,0.f,0.f,0.f,0.f,0.f,0.f};
  for (int n=0;n<32;++n){
    short8v vh = *(const short8v*)(Qh + base + (size_t)n*CD);
    short8v vl = *(const short8v*)(Ql + base + (size_t)n*CD);
    #pragma unroll
    for (int j=0;j<8;++j){
      float fh = __uint_as_float(((unsigned)(unsigned short)vh[j])<<16);
      float fl = __uint_as_float(((unsigned)(unsigned short)vl[j])<<16);
      s[j] += fh + fl;
    }
  }
  #pragma unroll
  for (int j=0;j<8;++j) red[ng][c8+j] = s[j];
  __syncthreads();
  float tot = 0.f;
  #pragma unroll
  for (int g=0;g<8;++g) tot += red[g][t];
  part[blockIdx.x*256 + t] = tot;
}

// ---- SE MLP ----
__global__ __launch_bounds__(256) void k_semlp(const float* __restrict__ part, const float* __restrict__ w1,
                                               const float* __restrict__ w2, float* __restrict__ se){
  __shared__ float sm[256];
  __shared__ float s1s[128];
  int b = blockIdx.x, t = threadIdx.x;
  float s = (part[(b*4+0)*256+t]+part[(b*4+1)*256+t])+(part[(b*4+2)*256+t]+part[(b*4+3)*256+t]);
  sm[t] = s*(1.0f/1024.0f);
  __syncthreads();
  if (t < 128){
    float a = 0.f;
    const float* wr = w1 + t*256;
    for (int c=0;c<256;c+=4){
      float4 wf = *(const float4*)(wr+c);
      a += sm[c]*wf.x + sm[c+1]*wf.y + sm[c+2]*wf.z + sm[c+3]*wf.w;
    }
    s1s[t] = fmaxf(a, 0.f);
  }
  __syncthreads();
  float a = 0.f;
  const float* wr2 = w2 + t*128;
  for (int c=0;c<128;c+=4){
    float4 wf = *(const float4*)(wr2+c);
    a += s1s[c]*wf.x + s1s[c+1]*wf.y + s1s[c+2]*wf.z + s1s[c+3]*wf.w;
  }
  se[b*256+t] = 1.0f/(1.0f+expf(-a));
}

// ---- conv 2x2/s2 as MFMA GEMM: tile 64m x 128n, K'=1024; 2-phase gload_lds pipeline ----
__global__ __launch_bounds__(256) void k_conv(const short* __restrict__ Qh, const short* __restrict__ Ql,
                                              const short* __restrict__ Wsh, const short* __restrict__ Wsl,
                                              const float* __restrict__ srb, float* __restrict__ xr){
  // per buffer (shorts): Ah@0 (64x32), Al@2048, Bh@4096 (128x32), Bl@8192; stride 12288
  __shared__ __align__(16) short smem[24576];   // 48KB, double-buffered
  int mblk = blockIdx.x >> 1, nblk = blockIdx.x & 1;
  int m0 = mblk*64, n0 = nblk*128;
  int b = mblk >> 2;
  int pos0 = m0 & 255;
  int t = threadIdx.x, wave = t>>6, lane = t&63;
  int wm = wave>>1, wn = wave&1;
  int q = lane>>4, r = lane&15;
  int lr = lane>>2;
  int sx = (lane>>3)&3;
  int lc = ((lane&3) ^ sx)*8;          // pre-swizzled source chunk
  int sw8 = ((r>>1)&3)*8;              // matching frag-read swizzle
  const f32x4 fz = {0.f,0.f,0.f,0.f};
  f32x4 acc[2][4];
  #pragma unroll
  for (int s=0;s<2;++s)
    #pragma unroll
    for (int tt=0;tt<4;++tt) acc[s][tt] = fz;

  auto stage = [&](int cur, int kc){
    short* sb = smem + cur*12288;
    short* wb = sb + wave*512;
    int g = kc>>3, cin0 = (kc&7)*32;
    int gh = g>>1, gw = g&1;
    int ra = wave*16 + lr;                       // 0..63
    int posA = pos0 + ra, hs = posA>>4, ws2 = posA&15;
    int tok = (2*hs+gh)*32 + 2*ws2 + gw;
    size_t ga = ((size_t)((b<<10) + tok))*CD + cin0 + lc;
    gl16(Qh + ga, wb);
    gl16(Ql + ga, wb + 2048);
    int ko = kc*32;
    #pragma unroll
    for (int rep=0; rep<2; ++rep){
      int rb = ra + rep*64;
      gl16(Wsh + (size_t)(n0+rb)*1024 + ko + lc, wb + 4096 + rep*2048);
      gl16(Wsl + (size_t)(n0+rb)*1024 + ko + lc, wb + 8192 + rep*2048);
    }
  };

  stage(0, 0);
  __syncthreads();
  int cur = 0;
  for (int kc=0; kc<32; ++kc){
    if (kc < 31) stage(cur^1, kc+1);
    const short* sb = smem + cur*12288;
    short8v ah[2], al[2];
    #pragma unroll
    for (int s=0;s<2;++s){
      int row = wm*32 + s*16 + r;
      ah[s] = *(const short8v*)(sb + row*32 + ((q*8)^sw8));
      al[s] = *(const short8v*)(sb + 2048 + row*32 + ((q*8)^sw8));
    }
    #pragma unroll
    for (int tt=0;tt<4;++tt){
      int brow = wn*64 + tt*16 + r;
      short8v bh = *(const short8v*)(sb + 4096 + brow*32 + ((q*8)^sw8));
      short8v bl = *(const short8v*)(sb + 8192 + brow*32 + ((q*8)^sw8));
      #pragma unroll
      for (int s=0;s<2;++s){
        acc[s][tt] = __builtin_amdgcn_mfma_f32_16x16x32_bf16(ah[s], bh, acc[s][tt], 0,0,0);
        acc[s][tt] = __builtin_amdgcn_mfma_f32_16x16x32_bf16(ah[s], bl, acc[s][tt], 0,0,0);
        acc[s][tt] = __builtin_amdgcn_mfma_f32_16x16x32_bf16(al[s], bh, acc[s][tt], 0,0,0);
      }
    }
    __syncthreads();
    cur ^= 1;
  }
  #pragma unroll
  for (int s=0;s<2;++s){
    #pragma unroll
    for (int tt=0;tt<4;++tt){
      int c = n0 + wn*64 + tt*16 + r;
      float bias = srb[c];
      #pragma unroll
      for (int i=0;i<4;++i){
        int m = m0 + wm*32 + s*16 + q*4 + i;
        xr[m*CD + c] = acc[s][tt][i] + bias;
      }
    }
  }
}

// ---- layernorm over C; reads xr fp32, writes bf16 hi/lo planes ----
__global__ __launch_bounds__(256) void k_ln(const float* __restrict__ xr, const float* __restrict__ g,
                                            const float* __restrict__ bta, short* __restrict__ Xh,
                                            short* __restrict__ Xl){
  int wv = threadIdx.x >> 6, lane = threadIdx.x & 63;
  int row = blockIdx.x*4 + wv;
  float4 v = ((const float4*)(xr + row*CD))[lane];
  float s = (v.x+v.y)+(v.z+v.w);
  #pragma unroll
  for (int off=1; off<64; off<<=1) s += __shfl_xor(s, off, 64);
  float mu = s * (1.0f/256.0f);
  float dx=v.x-mu, dy=v.y-mu, dz=v.z-mu, dw=v.w-mu;
  float s2 = (dx*dx+dy*dy)+(dz*dz+dw*dw);
  #pragma unroll
  for (int off=1; off<64; off<<=1) s2 += __shfl_xor(s2, off, 64);
  float inv = 1.0f / sqrtf(s2*(1.0f/256.0f) + 1e-5f);
  float4 gr = ((const float4*)g)[lane];
  float4 br = ((const float4*)bta)[lane];
  float o0 = dx*inv*gr.x + br.x;
  float o1 = dy*inv*gr.y + br.y;
  float o2 = dz*inv*gr.z + br.z;
  float o3 = dw*inv*gr.w + br.w;
  short4v h, l; short a0,b0;
  split2(o0,a0,b0); h[0]=a0; l[0]=b0;
  split2(o1,a0,b0); h[1]=a0; l[1]=b0;
  split2(o2,a0,b0); h[2]=a0; l[2]=b0;
  split2(o3,a0,b0); h[3]=a0; l[3]=b0;
  *(short4v*)(Xh + row*CD + lane*4) = h;
  *(short4v*)(Xl + row*CD + lane*4) = l;
}

// ---- Q proj MFMA: 128x128 tile; 2-phase gload_lds pipeline; head-major vectorized epilogue ----
__global__ __launch_bounds__(256) void k_qproj(const short* __restrict__ Qh, const short* __restrict__ Ql,
                                               const short* __restrict__ Wih, const short* __restrict__ Wil,
                                               const float* __restrict__ ipb,
                                               short* __restrict__ Qbh, short* __restrict__ Qbl){
  // per buffer (shorts): Ah@0, Al@4096, Bh@8192, Bl@12288 (each 128x32); stride 16384
  __shared__ __align__(16) short smem[32768];   // 64KB double-buffered; epilogue reuses first 32KB
  int mblk = blockIdx.x >> 1, nblk = blockIdx.x & 1;
  int m0 = mblk*128, n0 = nblk*128;
  int t = threadIdx.x, wave = t>>6, lane = t&63;
  int wm = wave>>1, wn = wave&1;
  int q = lane>>4, r = lane&15;
  int lr = lane>>2;
  int sx = (lane>>3)&3;
  int lc = ((lane&3) ^ sx)*8;
  int sw8 = ((r>>1)&3)*8;
  const f32x4 fz = {0.f,0.f,0.f,0.f};
  f32x4 acc[4][4];
  #pragma unroll
  for (int s=0;s<4;++s)
    #pragma unroll
    for (int tt=0;tt<4;++tt) acc[s][tt] = fz;

  auto stage = [&](int cur, int kc){
    int ko = kc*32;
    short* sb = smem + cur*16384;
    short* wb = sb + wave*512;
    #pragma unroll
    for (int rep=0; rep<2; ++rep){
      int ra = wave*16 + lr + rep*64;
      size_t ga = (size_t)(m0+ra)*CD + ko + lc;
      size_t gb = (size_t)(n0+ra)*CD + ko + lc;
      gl16(Qh  + ga, wb + rep*2048);
      gl16(Ql  + ga, wb + 4096  + rep*2048);
      gl16(Wih + gb, wb + 8192  + rep*2048);
      gl16(Wil + gb, wb + 12288 + rep*2048);
    }
  };

  stage(0, 0);
  __syncthreads();
  int cur = 0;
  for (int kc=0; kc<8; ++kc){
    if (kc < 7) stage(cur^1, kc+1);
    const short* sb = smem + cur*16384;
    short8v ah[4], al[4];
    #pragma unroll
    for (int s=0;s<4;++s){
      int row = wm*64 + s*16 + r;
      ah[s] = *(const short8v*)(sb + row*32 + ((q*8)^sw8));
      al[s] = *(const short8v*)(sb + 4096 + row*32 + ((q*8)^sw8));
    }
    #pragma unroll
    for (int tt=0;tt<4;++tt){
      int brow = wn*64 + tt*16 + r;
      short8v bh = *(const short8v*)(sb + 8192 + brow*32 + ((q*8)^sw8));
      short8v bl = *(const short8v*)(sb + 12288 + brow*32 + ((q*8)^sw8));
      #pragma unroll
      for (int s=0;s<4;++s){
        acc[s][tt] = __builtin_amdgcn_mfma_f32_16x16x32_bf16(ah[s], bh, acc[s][tt], 0,0,0);
        acc[s][tt] = __builtin_amdgcn_mfma_f32_16x16x32_bf16(ah[s], bl, acc[s][tt], 0,0,0);
        acc[s][tt] = __builtin_amdgcn_mfma_f32_16x16x32_bf16(al[s], bh, acc[s][tt], 0,0,0);
      }
    }
    __syncthreads();
    cur ^= 1;
  }
  // ---- epilogue: bias/relu/sc; hi plane via LDS transpose; then lo plane from residual ----
  const float sc = 0.17677669529663687f;
  short* T = smem;   // 128 rows x 128 shorts
  #pragma unroll
  for (int s=0;s<4;++s){
    #pragma unroll
    for (int tt=0;tt<4;++tt){
      int c_loc = wn*64 + tt*16 + r;
      int chunk = c_loc >> 3, cb = c_loc & 7;
      float bias = ipb[n0 + c_loc];
      #pragma unroll
      for (int i=0;i<4;++i){
        int m_loc = wm*64 + s*16 + q*4 + i;
        float val = fmaxf(acc[s][tt][i] + bias, 0.f)*sc;
        unsigned hu = bfr(val);
        T[m_loc*128 + ((chunk ^ (m_loc&7))<<3) + cb] = (short)hu;
        acc[s][tt][i] = val - __uint_as_float(hu<<16);
      }
    }
  }
  __syncthreads();
  {
    int mrl = (lane>>2);
    int ccl = lane&3;
    #pragma unroll
    for (int e=0;e<8;++e){
      int hl = e&3, mg = e>>2;
      int m_loc = wave*32 + mg*16 + mrl;
      int cc16 = hl*4 + ccl;
      short8v v = *(const short8v*)(T + m_loc*128 + ((cc16 ^ (m_loc&7))<<3));
      *(short8v*)(Qbh + ((size_t)((n0>>5)+hl))*2097152 + (size_t)(m0+m_loc)*32 + ccl*8) = v;
    }
  }
  __syncthreads();
  #pragma unroll
  for (int s=0;s<4;++s){
    #pragma unroll
    for (int tt=0;tt<4;++tt){
      int c_loc = wn*64 + tt*16 + r;
      int chunk = c_loc >> 3, cb = c_loc & 7;
      #pragma unroll
      for (int i=0;i<4;++i){
        int m_loc = wm*64 + s*16 + q*4 + i;
        T[m_loc*128 + ((chunk ^ (m_loc&7))<<3) + cb] = (short)bfr(acc[s][tt][i]);
      }
    }
  }
  __syncthreads();
  {
    int mrl = (lane>>2);
    int ccl = lane&3;
    #pragma unroll
    for (int e=0;e<8;++e){
      int hl = e&3, mg = e>>2;
      int m_loc = wave*32 + mg*16 + mrl;
      int cc16 = hl*4 + ccl;
      short8v v = *(const short8v*)(T + m_loc*128 + ((cc16 ^ (m_loc&7))<<3));
      *(short8v*)(Qbl + ((size_t)((n0>>5)+hl))*2097152 + (size_t)(m0+m_loc)*32 + ccl*8) = v;
    }
  }
}

// ---- K/V proj MFMA: 2-phase gload_lds pipeline; N=512 ----
__global__ __launch_bounds__(256) void k_kvproj(const short* __restrict__ Xh, const short* __restrict__ Xl,
                                                const short* __restrict__ Wkh, const short* __restrict__ Wkl,
                                                const float* __restrict__ ipb, float* __restrict__ kb,
                                                float* __restrict__ vb){
  __shared__ __align__(16) short smem[32768];   // 64KB double-buffered
  int mblk = blockIdx.x >> 2, nblk = blockIdx.x & 3;
  int m0 = mblk*128, n0 = nblk*128;
  int t = threadIdx.x, wave = t>>6, lane = t&63;
  int wm = wave>>1, wn = wave&1;
  int q = lane>>4, r = lane&15;
  int lr = lane>>2;
  int sx = (lane>>3)&3;
  int lc = ((lane&3) ^ sx)*8;
  int sw8 = ((r>>1)&3)*8;
  const f32x4 fz = {0.f,0.f,0.f,0.f};
  f32x4 acc[4][4];
  #pragma unroll
  for (int s=0;s<4;++s)
    #pragma unroll
    for (int tt=0;tt<4;++tt) acc[s][tt] = fz;

  auto stage = [&](int cur, int kc){
    int ko = kc*32;
    short* sb = smem + cur*16384;
    short* wb = sb + wave*512;
    #pragma unroll
    for (int rep=0; rep<2; ++rep){
      int ra = wave*16 + lr + rep*64;
      size_t ga = (size_t)(m0+ra)*CD + ko + lc;
      size_t gb = (size_t)(n0+ra)*CD + ko + lc;
      gl16(Xh  + ga, wb + rep*2048);
      gl16(Xl  + ga, wb + 4096  + rep*2048);
      gl16(Wkh + gb, wb + 8192  + rep*2048);
      gl16(Wkl + gb, wb + 12288 + rep*2048);
    }
  };

  stage(0, 0);
  __syncthreads();
  int cur = 0;
  for (int kc=0; kc<8; ++kc){
    if (kc < 7) stage(cur^1, kc+1);
    const short* sb = smem + cur*16384;
    short8v ah[4], al[4];
    #pragma unroll
    for (int s=0;s<4;++s){
      int row = wm*64 + s*16 + r;
      ah[s] = *(const short8v*)(sb + row*32 + ((q*8)^sw8));
      al[s] = *(const short8v*)(sb + 4096 + row*32 + ((q*8)^sw8));
    }
    #pragma unroll
    for (int tt=0;tt<4;++tt){
      int brow = wn*64 + tt*16 + r;
      short8v bh = *(const short8v*)(sb + 8192 + brow*32 + ((q*8)^sw8));
      short8v bl = *(const short8v*)(sb + 12288 + brow*32 + ((q*8)^sw8));
      #pragma unroll
      for (int s=0;s<4;++s){
        acc[s][tt] = __builtin_amdgcn_mfma_f32_16x16x32_bf16(ah[s], bh, acc[s][tt], 0,0,0);
        acc[s][tt] = __builtin_amdgcn_mfma_f32_16x16x32_bf16(ah[s], bl, acc[s][tt], 0,0,0);
        acc[s][tt] = __builtin_amdgcn_mfma_f32_16x16x32_bf16(al[s], bh, acc[s][tt], 0,0,0);
      }
    }
    __syncthreads();
    cur ^= 1;
  }
  #pragma unroll
  for (int s=0;s<4;++s){
    #pragma unroll
    for (int tt=0;tt<4;++tt){
      int c = n0 + wn*64 + tt*16 + r;       // 0..511
      float bias = ipb[256 + c];
      #pragma unroll
      for (int i=0;i<4;++i){
        int m = m0 + wm*64 + s*16 + q*4 + i;
        float v = acc[s][tt][i] + bias;
        if (c < 256) kb[m*CD + c] = fmaxf(v, 0.f);
        else         vb[m*CD + (c-256)] = v;
      }
    }
  }
}

// ---- kv -> B planes for attn MFMA: B[bh][r][j], r = p*32+m (kv), 128+p (ksum), 132..143 zero ----
__global__ __launch_bounds__(256) void k_kv(const float* __restrict__ kb, const float* __restrict__ vbuf,
                                            const float* __restrict__ t2, short* __restrict__ Bhp,
                                            short* __restrict__ Blp){
  int bh = blockIdx.x; int b = bh >> 3, h = bh & 7;
  int t = threadIdx.x; int jq = t >> 5, m = t & 31;
  float acc[4][4];
  #pragma unroll
  for (int p=0;p<4;++p){ acc[p][0]=0.f; acc[p][1]=0.f; acc[p][2]=0.f; acc[p][3]=0.f; }
  const float* kbase = kb + h*HDIM + jq*4;
  const float* vbase = vbuf + h*HDIM + m;
  for (int n=0;n<256;++n){
    int ro = (b*NS + n)*CD;
    float4 k4 = *(const float4*)(kbase + ro);
    float vv = vbase[ro];
    float4 tt = *(const float4*)(t2 + n*4);
    float tv[4] = {tt.x, tt.y, tt.z, tt.w};
    float kk[4] = {k4.x, k4.y, k4.z, k4.w};
    #pragma unroll
    for (int p=0;p<4;++p){
      float tp = tv[p]*vv;
      #pragma unroll
      for (int jj=0;jj<4;++jj) acc[p][jj] += tp*kk[jj];
    }
  }
  short* bhb = Bhp + bh*4608;
  short* blb = Blp + bh*4608;
  #pragma unroll
  for (int p=0;p<4;++p){
    short4v h4, l4;
    #pragma unroll
    for (int jj=0;jj<4;++jj){ short a,bq; split2(acc[p][jj],a,bq); h4[jj]=a; l4[jj]=bq; }
    *(short4v*)(bhb + (p*32+m)*32 + jq*4) = h4;
    *(short4v*)(blb + (p*32+m)*32 + jq*4) = l4;
  }
  if (t < 128){
    int p = t >> 5, j = t & 31;
    float s=0.f;
    const float* kp = kb + h*HDIM + j;
    for (int n=0;n<256;++n) s += t2[n*4+p]*kp[(b*NS+n)*CD];
    short a,bq; split2(s,a,bq);
    bhb[(128+p)*32 + j] = a;
    blb[(128+p)*32 + j] = bq;
  } else {
    int idx = t - 128;       // zero pad rows 132..143 (384 shorts per plane)
    #pragma unroll
    for (int ii=0;ii<3;++ii){
      bhb[4224 + idx*3 + ii] = 0;
      blb[4224 + idx*3 + ii] = 0;
    }
  }
}

// ---- attn as MFMA GEMM per (b,h): A = Q head planes (M=1024,K=32), B = kv planes (N=144) ----
__global__ __launch_bounds__(256) void k_attn(const short* __restrict__ Qbh, const short* __restrict__ Qbl,
                                              const short* __restrict__ Bhg, const short* __restrict__ Blg,
                                              const float* __restrict__ t1,
                                              short* __restrict__ Ath, short* __restrict__ Atl){
  __shared__ __align__(16) short Bh[144*32];
  __shared__ __align__(16) short Bl[144*32];
  __shared__ __align__(16) short Ah[256*32];
  __shared__ __align__(16) short Al[256*32];
  int bh = blockIdx.x, b = bh>>3, h = bh&7;
  int t = threadIdx.x, lane = t&63, wave = t>>6;
  int q = lane>>4, r = lane&15;
  {
    const short8v* sh = (const short8v*)(Bhg + bh*4608);
    const short8v* sl = (const short8v*)(Blg + bh*4608);
    for (int i=t; i<576; i+=256){
      ((short8v*)Bh)[i] = sh[i];
      ((short8v*)Bl)[i] = sl[i];
    }
  }
  __syncthreads();
  short8v bf_h[9], bf_l[9];
  #pragma unroll
  for (int nt=0; nt<9; ++nt){
    int row = nt*16 + r;
    bf_h[nt] = *(const short8v*)(Bh + row*32 + q*8);
    bf_l[nt] = *(const short8v*)(Bl + row*32 + q*8);
  }
  const short* qh_base = Qbh + ((size_t)h*65536 + (size_t)b*1024)*32;
  const short* ql_base = Qbl + ((size_t)h*65536 + (size_t)b*1024)*32;
  const f32x4 fz = {0.f,0.f,0.f,0.f};
  for (int u=0; u<4; ++u){
    __syncthreads();
    {
      const short8v* sh = (const short8v*)(qh_base + (u*256 + t)*32);
      const short8v* sl = (const short8v*)(ql_base + (u*256 + t)*32);
      short8v* dh = (short8v*)(Ah + t*32);
      short8v* dl = (short8v*)(Al + t*32);
      #pragma unroll
      for (int i=0;i<4;++i){ dh[i]=sh[i]; dl[i]=sl[i]; }
    }
    __syncthreads();
    #pragma unroll
    for (int mi=0; mi<4; ++mi){
      int mt = wave*4 + mi;
      short8v ah = *(const short8v*)(Ah + (mt*16 + r)*32 + q*8);
      short8v al = *(const short8v*)(Al + (mt*16 + r)*32 + q*8);
      f32x4 acc[9];
      #pragma unroll
      for (int nt=0;nt<9;++nt) acc[nt]=fz;
      #pragma unroll
      for (int nt=0;nt<9;++nt){
        acc[nt] = __builtin_amdgcn_mfma_f32_16x16x32_bf16(ah, bf_h[nt], acc[nt],0,0,0);
        acc[nt] = __builtin_amdgcn_mfma_f32_16x16x32_bf16(ah, bf_l[nt], acc[nt],0,0,0);
        acc[nt] = __builtin_amdgcn_mfma_f32_16x16x32_bf16(al, bf_h[nt], acc[nt],0,0,0);
      }
      int nbase = u*256 + mt*16 + q*4;
      int src = lane & 48;
      #pragma unroll
      for (int i=0;i<4;++i){
        int n = nbase + i;
        float4 tv = *(const float4*)(t1 + n*4);
        float dp0 = __shfl(acc[8][i], src+0, 64);
        float dp1 = __shfl(acc[8][i], src+1, 64);
        float dp2 = __shfl(acc[8][i], src+2, 64);
        float dp3 = __shfl(acc[8][i], src+3, 64);
        float den = tv.x*dp0 + tv.y*dp1 + tv.z*dp2 + tv.w*dp3;
        float a0 = tv.x*acc[0][i] + tv.y*acc[2][i] + tv.z*acc[4][i] + tv.w*acc[6][i];
        float a1 = tv.x*acc[1][i] + tv.y*acc[3][i] + tv.z*acc[5][i] + tv.w*acc[7][i];
        float sgn = (den>0.f) ? 1.f : ((den<0.f)? -1.f : 0.f);
        float ad = fminf(fmaxf(fabsf(den), 1e-4f), 1e4f);
        float inv = (den != 0.f) ? 1.0f/(ad*sgn) : 0.f;
        float o0 = a0*inv, o1 = a1*inv;
        int mrow = b*NTOK + n;
        short h0,l0,h1,l1;
        split2(o0,h0,l0); split2(o1,h1,l1);
        Ath[mrow*CD + h*HDIM + r]      = h0;
        Atl[mrow*CD + h*HDIM + r]      = l0;
        Ath[mrow*CD + h*HDIM + 16 + r] = h1;
        Atl[mrow*CD + h*HDIM + 16 + r] = l1;
      }
    }
  }
}

// ---- out proj MFMA: 2-phase gload_lds pipeline; +bias, *se, transpose store ----
__global__ __launch_bounds__(256) void k_outproj(const short* __restrict__ Ath, const short* __restrict__ Atl,
                                                 const short* __restrict__ Woh, const short* __restrict__ Wol,
                                                 const float* __restrict__ obv, const float* __restrict__ se,
                                                 float* __restrict__ dout){
  __shared__ __align__(16) short smem[32768];   // 64KB double-buffered
  int mblk = blockIdx.x >> 1, nblk = blockIdx.x & 1;
  int m0 = mblk*128, n0 = nblk*128;
  int t = threadIdx.x, wave = t>>6, lane = t&63;
  int wm = wave>>1, wn = wave&1;
  int q = lane>>4, r = lane&15;
  int lr = lane>>2;
  int sx = (lane>>3)&3;
  int lc = ((lane&3) ^ sx)*8;
  int sw8 = ((r>>1)&3)*8;
  const f32x4 fz = {0.f,0.f,0.f,0.f};
  f32x4 acc[4][4];
  #pragma unroll
  for (int s=0;s<4;++s)
    #pragma unroll
    for (int tt=0;tt<4;++tt) acc[s][tt] = fz;

  auto stage = [&](int cur, int kc){
    int ko = kc*32;
    short* sb = smem + cur*16384;
    short* wb = sb + wave*512;
    #pragma unroll
    for (int rep=0; rep<2; ++rep){
      int ra = wave*16 + lr + rep*64;
      size_t ga = (size_t)(m0+ra)*CD + ko + lc;
      size_t gb = (size_t)(n0+ra)*CD + ko + lc;
      gl16(Ath + ga, wb + rep*2048);
      gl16(Atl + ga, wb + 4096  + rep*2048);
      gl16(Woh + gb, wb + 8192  + rep*2048);
      gl16(Wol + gb, wb + 12288 + rep*2048);
    }
  };

  stage(0, 0);
  __syncthreads();
  int cur = 0;
  for (int kc=0; kc<8; ++kc){
    if (kc < 7) stage(cur^1, kc+1);
    const short* sb = smem + cur*16384;
    short8v ah[4], al[4];
    #pragma unroll
    for (int s=0;s<4;++s){
      int row = wm*64 + s*16 + r;
      ah[s] = *(const short8v*)(sb + row*32 + ((q*8)^sw8));
      al[s] = *(const short8v*)(sb + 4096 + row*32 + ((q*8)^sw8));
    }
    #pragma unroll
    for (int tt=0;tt<4;++tt){
      int brow = wn*64 + tt*16 + r;
      short8v bh = *(const short8v*)(sb + 8192 + brow*32 + ((q*8)^sw8));
      short8v bl = *(const short8v*)(sb + 12288 + brow*32 + ((q*8)^sw8));
      #pragma unroll
      for (int s=0;s<4;++s){
        acc[s][tt] = __builtin_amdgcn_mfma_f32_16x16x32_bf16(ah[s], bh, acc[s][tt], 0,0,0);
        acc[s][tt] = __builtin_amdgcn_mfma_f32_16x16x32_bf16(ah[s], bl, acc[s][tt], 0,0,0);
        acc[s][tt] = __builtin_amdgcn_mfma_f32_16x16x32_bf16(al[s], bh, acc[s][tt], 0,0,0);
      }
    }
    __syncthreads();
    cur ^= 1;
  }
  #pragma unroll
  for (int s=0;s<4;++s){
    #pragma unroll
    for (int tt=0;tt<4;++tt){
      int c = n0 + wn*64 + tt*16 + r;
      float bias = obv[c];
      #pragma unroll
      for (int i=0;i<4;++i){
        int m = m0 + wm*64 + s*16 + q*4 + i;
        int bb = m >> 10, ntok = m & 1023;
        float sev = se[bb*CD + c];
        dout[(ntok*NB + bb)*CD + c] = (acc[s][tt][i] + bias)*sev;
      }
    }
  }
}

extern "C" void kernel_launch(void* const* d_in, const int* in_sizes, int n_in,
                              void* d_out, int out_size, void* d_ws, size_t ws_size,
                              hipStream_t stream) {
  const float* query = (const float*)d_in[0];
  const float* ipw = (const float*)d_in[5];
  const float* ipb = (const float*)d_in[6];
  const float* srw = (const float*)d_in[7];
  const float* srb = (const float*)d_in[8];
  const float* ng  = (const float*)d_in[9];
  const float* nbb = (const float*)d_in[10];
  const float* ow  = (const float*)d_in[11];
  const float* obv = (const float*)d_in[12];
  const float* sw1 = (const float*)d_in[13];
  const float* sw2 = (const float*)d_in[14];
  float* dout = (float*)d_out;
  float* ws = (float*)d_ws;

  // ---- workspace layout (float offsets; end 44,913,664 f < proven 48.4M) ----
  short* Qbh  = (short*)ws;                // 16.7M shorts: q head planes [h][m][32] [qproj -> attn]
  short* Qbl  = (short*)(ws + 8388608);
  float* R1   = ws + 16777216;             // 16,777,216 f  multi-use region
  short* Qh   = (short*)R1;                //  Q hi plane (16.7M shorts)  [qcvt -> semean/qproj/conv]
  short* Ql   = (short*)(R1 + 8388608);    //  Q lo plane
  float* kb   = R1;                        //  4,194,304 f  [kvproj -> k_kv]  (after Q planes dead)
  float* vb   = R1 + 4194304;              //  4,194,304 f  [kvproj -> k_kv]
  short* Ath  = (short*)R1;                //  At hi plane [attn -> outproj] (after kb/vb dead)
  short* Atl  = (short*)(R1 + 8388608);    //  At lo plane
  float* xr   = ws + 33554432;             //  4,194,304 f  [conv -> ln]
  short* Xh   = (short*)(ws + 37748736);   //  [ln -> kvproj]
  short* Xl   = (short*)(ws + 39845888);
  short* kvbh = (short*)(ws + 41943040);   //  512x144x32 shorts = 1,179,648 f [k_kv -> attn]
  short* kvbl = (short*)(ws + 43122688);
  float* part = ws + 44302336;             //     65,536 f
  float* se   = ws + 44367872;             //     16,384 f
  float* t1   = ws + 44384256;             //      4,096 f
  float* t2   = ws + 44388352;             //      1,024 f
  short* Wih  = (short*)(ws + 44389376);   // 768x256
  short* Wil  = (short*)(ws + 44487680);
  short* Woh  = (short*)(ws + 44585984);   // 256x256
  short* Wol  = (short*)(ws + 44618752);
  short* Wsh  = (short*)(ws + 44651520);   // 256x1024
  short* Wsl  = (short*)(ws + 44782592);   // end: 44,913,664 f

  k_wcvt  <<<256,  256,0,stream>>>(ipw, ow, srw, Wih, Wil, Woh, Wol, Wsh, Wsl);
  k_qcvt  <<<8192, 256,0,stream>>>(query, Qh, Ql);
  k_trig  <<<4,    256,0,stream>>>(t1, t2);
  k_semean<<<256,  256,0,stream>>>(Qh, Ql, part);
  k_semlp <<<64,   256,0,stream>>>(part, sw1, sw2, se);
  k_conv  <<<512,  256,0,stream>>>(Qh, Ql, Wsh, Wsl, srb, xr);
  k_ln    <<<4096, 256,0,stream>>>(xr, ng, nbb, Xh, Xl);
  k_qproj <<<1024, 256,0,stream>>>(Qh, Ql, Wih, Wil, ipb, Qbh, Qbl);  // before kvproj (kb/vb overlay Q planes)
  k_kvproj<<<512,  256,0,stream>>>(Xh, Xl, Wih + 256*CD, Wil + 256*CD, ipb, kb, vb);
  k_kv    <<<512,  256,0,stream>>>(kb, vb, t2, kvbh, kvbl);
  k_attn  <<<512,  256,0,stream>>>(Qbh, Qbl, kvbh, kvbl, t1, Ath, Atl);
  k_outproj<<<1024,256,0,stream>>>(Ath, Atl, Woh, Wol, obv, se, dout);
}

// Round 4
// 458.286 us; speedup vs baseline: 1.0160x; 1.0160x over previous
//
#include <hip/hip_runtime.h>

#define NTOK 1024
#define NB   64
#define CD   256
#define NHEAD 8
#define HDIM 32
#define NS 256
#define NBC 16384

typedef __attribute__((ext_vector_type(8))) short short8v;
typedef __attribute__((ext_vector_type(4))) short short4v;
typedef __attribute__((ext_vector_type(4))) float f32x4;

// round-to-nearest-even fp32 -> bf16 (low 16 bits returned)
__device__ __forceinline__ unsigned bfr(float x){
  unsigned u = __float_as_uint(x);
  return (u + 0x7fffu + ((u>>16)&1u)) >> 16;
}
// two-term split: x ~= hi + lo, both bf16
__device__ __forceinline__ void split2(float x, short &h, short &l){
  unsigned hu = bfr(x);
  float hf = __uint_as_float(hu << 16);
  unsigned lu = bfr(x - hf);
  h = (short)hu; l = (short)lu;
}

// ---- weights -> bf16 hi/lo planes (row-major [n][k]) ----
__global__ __launch_bounds__(256) void k_wcvt(const float* __restrict__ ipw, const float* __restrict__ ow,
                                              const float* __restrict__ srw,
                                              short* __restrict__ Wih, short* __restrict__ Wil,
                                              short* __restrict__ Woh, short* __restrict__ Wol,
                                              short* __restrict__ Wsh, short* __restrict__ Wsl){
  int u = blockIdx.x*256 + threadIdx.x;   // 65536 units of 8 elements
  float xs[8];
  short* dh; short* dl; int dof;
  if (u < 24576){
    int n = u >> 5, off = (u & 31)*8;
    const float* s = ipw + n*CD + off;
    #pragma unroll
    for (int i=0;i<8;++i) xs[i] = s[i];
    dh = Wih; dl = Wil; dof = n*CD + off;
  } else if (u < 32768){
    int v = u - 24576;
    int n = v >> 5, off = (v & 31)*8;
    const float* s = ow + n*CD + off;
    #pragma unroll
    for (int i=0;i<8;++i) xs[i] = s[i];
    dh = Woh; dl = Wol; dof = n*CD + off;
  } else {
    int v = u - 32768;
    int n = v >> 7, koff = (v & 127)*8;
    int g = koff >> 8, cin0 = koff & 255;
    #pragma unroll
    for (int i=0;i<8;++i) xs[i] = srw[n*1024 + (cin0+i)*4 + g];
    dh = Wsh; dl = Wsl; dof = n*1024 + koff;
  }
  short8v h, l;
  #pragma unroll
  for (int i=0;i<8;++i){ short a,b; split2(xs[i],a,b); h[i]=a; l[i]=b; }
  *(short8v*)(dh + dof) = h;
  *(short8v*)(dl + dof) = l;
}

// ---- trig tables ----
__global__ __launch_bounds__(256) void k_trig(float* __restrict__ t1, float* __restrict__ t2){
  int n = blockIdx.x*256 + threadIdx.x;
  const float c = 1.57079632679489662f;
  float aa = c * (float)(n >> 5) / 32.0f;
  float bb = c * (float)(n & 31) / 32.0f;
  t1[n*4+0]=cosf(aa); t1[n*4+1]=sinf(aa); t1[n*4+2]=cosf(bb); t1[n*4+3]=sinf(bb);
  if (n < 256){
    float a2 = c * (float)(n >> 4) / 16.0f;
    float b2 = c * (float)(n & 15) / 16.0f;
    t2[n*4+0]=cosf(a2); t2[n*4+1]=sinf(a2); t2[n*4+2]=cosf(b2); t2[n*4+3]=sinf(b2);
  }
}

// ---- SE: partial mean over tokens of raw fp32 query ----
__global__ __launch_bounds__(256) void k_semean(const float* __restrict__ q, float* __restrict__ part){
  int b = blockIdx.x >> 2, qr = blockIdx.x & 3;
  int c = threadIdx.x;
  const float* qp = q + (qr*256)*NBC + b*CD + c;
  float s0=0.f,s1=0.f,s2=0.f,s3=0.f;
  for (int n=0;n<256;n+=4){
    s0 += qp[(n  )*NBC];
    s1 += qp[(n+1)*NBC];
    s2 += qp[(n+2)*NBC];
    s3 += qp[(n+3)*NBC];
  }
  part[blockIdx.x*256 + c] = (s0+s1)+(s2+s3);
}

// ---- SE MLP ----
__global__ __launch_bounds__(256) void k_semlp(const float* __restrict__ part, const float* __restrict__ w1,
                                               const float* __restrict__ w2, float* __restrict__ se){
  __shared__ float sm[256];
  __shared__ float s1s[128];
  int b = blockIdx.x, t = threadIdx.x;
  float s = (part[(b*4+0)*256+t]+part[(b*4+1)*256+t])+(part[(b*4+2)*256+t]+part[(b*4+3)*256+t]);
  sm[t] = s*(1.0f/1024.0f);
  __syncthreads();
  if (t < 128){
    float a = 0.f;
    const float* wr = w1 + t*256;
    for (int c=0;c<256;c+=4){
      float4 wf = *(const float4*)(wr+c);
      a += sm[c]*wf.x + sm[c+1]*wf.y + sm[c+2]*wf.z + sm[c+3]*wf.w;
    }
    s1s[t] = fmaxf(a, 0.f);
  }
  __syncthreads();
  float a = 0.f;
  const float* wr2 = w2 + t*128;
  for (int c=0;c<128;c+=4){
    float4 wf = *(const float4*)(wr2+c);
    a += s1s[c]*wf.x + s1s[c+1]*wf.y + s1s[c+2]*wf.z + s1s[c+3]*wf.w;
  }
  se[b*256+t] = 1.0f/(1.0f+expf(-a));
}

// ---- conv 2x2/s2 as MFMA GEMM: tile 64m x 128n, K'=1024; A staged from fp32 query + split2 ----
__global__ __launch_bounds__(256) void k_conv(const float* __restrict__ qf,
                                              const short* __restrict__ Wsh, const short* __restrict__ Wsl,
                                              const float* __restrict__ srb, float* __restrict__ xr){
  __shared__ __align__(16) short Ah[64*32];
  __shared__ __align__(16) short Al[64*32];
  __shared__ __align__(16) short Bh[128*32];
  __shared__ __align__(16) short Bl[128*32];
  int mblk = blockIdx.x >> 1, nblk = blockIdx.x & 1;
  int m0 = mblk*64, n0 = nblk*128;
  int b = mblk >> 2;
  int pos0 = m0 & 255;
  int t = threadIdx.x, wave = t>>6, lane = t&63;
  int wm = wave>>1, wn = wave&1;
  int q = lane>>4, r = lane&15;
  int ra = t>>2, pa = (t&3)*8;
  int posA = pos0 + ra, hs = posA>>4, ws2 = posA&15;
  const f32x4 fz = {0.f,0.f,0.f,0.f};
  f32x4 acc[2][4];
  #pragma unroll
  for (int s=0;s<2;++s)
    #pragma unroll
    for (int tt=0;tt<4;++tt) acc[s][tt] = fz;
  for (int kc=0; kc<32; ++kc){
    int g = kc>>3, cin0 = (kc&7)*32;
    int gh = g>>1, gw = g&1;
    int tok = (2*hs+gh)*32 + 2*ws2 + gw;
    const float* src = qf + (size_t)tok*NBC + b*CD + cin0 + pa;
    float4 fa = *(const float4*)src;
    float4 fb = *(const float4*)(src+4);
    float xs[8] = {fa.x,fa.y,fa.z,fa.w,fb.x,fb.y,fb.z,fb.w};
    short8v hh, ll;
    #pragma unroll
    for (int i=0;i<8;++i){ short a0,b0; split2(xs[i],a0,b0); hh[i]=a0; ll[i]=b0; }
    *(short8v*)(Ah + ra*32 + pa) = hh;
    *(short8v*)(Al + ra*32 + pa) = ll;
    int ko = kc*32;
    #pragma unroll
    for (int rep=0; rep<2; ++rep){
      int rr = ra + rep*64;
      int gb = (n0 + rr)*1024 + ko + pa;
      *(short8v*)(Bh + rr*32 + pa) = *(const short8v*)(Wsh + gb);
      *(short8v*)(Bl + rr*32 + pa) = *(const short8v*)(Wsl + gb);
    }
    __syncthreads();
    short8v ah[2], al[2];
    #pragma unroll
    for (int s=0;s<2;++s){
      int row = wm*32 + s*16 + r;
      ah[s] = *(const short8v*)(Ah + row*32 + q*8);
      al[s] = *(const short8v*)(Al + row*32 + q*8);
    }
    #pragma unroll
    for (int tt=0;tt<4;++tt){
      int brow = wn*64 + tt*16 + r;
      short8v bh = *(const short8v*)(Bh + brow*32 + q*8);
      short8v bl = *(const short8v*)(Bl + brow*32 + q*8);
      #pragma unroll
      for (int s=0;s<2;++s){
        acc[s][tt] = __builtin_amdgcn_mfma_f32_16x16x32_bf16(ah[s], bh, acc[s][tt], 0,0,0);
        acc[s][tt] = __builtin_amdgcn_mfma_f32_16x16x32_bf16(ah[s], bl, acc[s][tt], 0,0,0);
        acc[s][tt] = __builtin_amdgcn_mfma_f32_16x16x32_bf16(al[s], bh, acc[s][tt], 0,0,0);
      }
    }
    __syncthreads();
  }
  #pragma unroll
  for (int s=0;s<2;++s){
    #pragma unroll
    for (int tt=0;tt<4;++tt){
      int c = n0 + wn*64 + tt*16 + r;
      float bias = srb[c];
      #pragma unroll
      for (int i=0;i<4;++i){
        int m = m0 + wm*32 + s*16 + q*4 + i;
        xr[m*CD + c] = acc[s][tt][i] + bias;
      }
    }
  }
}

// ---- layernorm over C; reads xr fp32, writes bf16 hi/lo planes ----
__global__ __launch_bounds__(256) void k_ln(const float* __restrict__ xr, const float* __restrict__ g,
                                            const float* __restrict__ bta, short* __restrict__ Xh,
                                            short* __restrict__ Xl){
  int wv = threadIdx.x >> 6, lane = threadIdx.x & 63;
  int row = blockIdx.x*4 + wv;
  float4 v = ((const float4*)(xr + row*CD))[lane];
  float s = (v.x+v.y)+(v.z+v.w);
  #pragma unroll
  for (int off=1; off<64; off<<=1) s += __shfl_xor(s, off, 64);
  float mu = s * (1.0f/256.0f);
  float dx=v.x-mu, dy=v.y-mu, dz=v.z-mu, dw=v.w-mu;
  float s2 = (dx*dx+dy*dy)+(dz*dz+dw*dw);
  #pragma unroll
  for (int off=1; off<64; off<<=1) s2 += __shfl_xor(s2, off, 64);
  float inv = 1.0f / sqrtf(s2*(1.0f/256.0f) + 1e-5f);
  float4 gr = ((const float4*)g)[lane];
  float4 br = ((const float4*)bta)[lane];
  float o0 = dx*inv*gr.x + br.x;
  float o1 = dy*inv*gr.y + br.y;
  float o2 = dz*inv*gr.z + br.z;
  float o3 = dw*inv*gr.w + br.w;
  short4v h, l; short a0,b0;
  split2(o0,a0,b0); h[0]=a0; l[0]=b0;
  split2(o1,a0,b0); h[1]=a0; l[1]=b0;
  split2(o2,a0,b0); h[2]=a0; l[2]=b0;
  split2(o3,a0,b0); h[3]=a0; l[3]=b0;
  *(short4v*)(Xh + row*CD + lane*4) = h;
  *(short4v*)(Xl + row*CD + lane*4) = l;
}

// ---- Q proj MFMA: 128x128 tile; A staged from fp32 query + split2; swizzled staging;
//      epilogue: relu,*sc,split2 -> LDS transpose -> vectorized head-major stores [h][m][32] ----
__global__ __launch_bounds__(256) void k_qproj(const float* __restrict__ qf,
                                               const short* __restrict__ Wih, const short* __restrict__ Wil,
                                               const float* __restrict__ ipb,
                                               short* __restrict__ Qbh, short* __restrict__ Qbl){
  __shared__ __align__(16) short smem[16384];   // 32KB: 4x(128x32) staging, then 128x128 transpose tile
  short* Ah = smem;
  short* Al = smem + 4096;
  short* Bh = smem + 8192;
  short* Bl = smem + 12288;
  int mblk = blockIdx.x >> 1, nblk = blockIdx.x & 1;
  int m0 = mblk*128, n0 = nblk*128;
  int t = threadIdx.x, wave = t>>6, lane = t&63;
  int wm = wave>>1, wn = wave&1;
  int q = lane>>4, r = lane&15;
  int cr = t>>2, cp = (t&3)*8;
  int cpS = (((t&3) ^ ((cr>>1)&3)))*8;       // swizzled staging-write chunk
  int sw8 = ((r>>1)&3)*8;                    // lane-constant fragment-read swizzle
  const f32x4 fz = {0.f,0.f,0.f,0.f};
  f32x4 acc[4][4];
  #pragma unroll
  for (int s=0;s<4;++s)
    #pragma unroll
    for (int tt=0;tt<4;++tt) acc[s][tt] = fz;
  for (int kc=0; kc<8; ++kc){
    int ko = kc*32;
    #pragma unroll
    for (int rep=0; rep<2; ++rep){
      int rr = cr + rep*64;
      int m = m0 + rr;
      const float* src = qf + (size_t)(m & 1023)*NBC + (m >> 10)*CD + ko + cp;
      float4 fa = *(const float4*)src;
      float4 fb = *(const float4*)(src+4);
      float xs[8] = {fa.x,fa.y,fa.z,fa.w,fb.x,fb.y,fb.z,fb.w};
      short8v hh, ll;
      #pragma unroll
      for (int i=0;i<8;++i){ short a0,b0; split2(xs[i],a0,b0); hh[i]=a0; ll[i]=b0; }
      *(short8v*)(Ah + rr*32 + cpS) = hh;
      *(short8v*)(Al + rr*32 + cpS) = ll;
      int gb = (n0 + rr)*CD + ko + cp;
      *(short8v*)(Bh + rr*32 + cpS) = *(const short8v*)(Wih + gb);
      *(short8v*)(Bl + rr*32 + cpS) = *(const short8v*)(Wil + gb);
    }
    __syncthreads();
    short8v ah[4], al[4];
    #pragma unroll
    for (int s=0;s<4;++s){
      int row = wm*64 + s*16 + r;
      ah[s] = *(const short8v*)(Ah + row*32 + ((q*8)^sw8));
      al[s] = *(const short8v*)(Al + row*32 + ((q*8)^sw8));
    }
    #pragma unroll
    for (int tt=0;tt<4;++tt){
      int brow = wn*64 + tt*16 + r;
      short8v bh = *(const short8v*)(Bh + brow*32 + ((q*8)^sw8));
      short8v bl = *(const short8v*)(Bl + brow*32 + ((q*8)^sw8));
      #pragma unroll
      for (int s=0;s<4;++s){
        acc[s][tt] = __builtin_amdgcn_mfma_f32_16x16x32_bf16(ah[s], bh, acc[s][tt], 0,0,0);
        acc[s][tt] = __builtin_amdgcn_mfma_f32_16x16x32_bf16(ah[s], bl, acc[s][tt], 0,0,0);
        acc[s][tt] = __builtin_amdgcn_mfma_f32_16x16x32_bf16(al[s], bh, acc[s][tt], 0,0,0);
      }
    }
    __syncthreads();
  }
  // ---- epilogue: bias/relu/sc; hi plane via LDS transpose; then lo plane from residual ----
  const float sc = 0.17677669529663687f;
  short* T = smem;   // 128 rows x 128 shorts
  #pragma unroll
  for (int s=0;s<4;++s){
    #pragma unroll
    for (int tt=0;tt<4;++tt){
      int c_loc = wn*64 + tt*16 + r;
      int chunk = c_loc >> 3, cb = c_loc & 7;
      float bias = ipb[n0 + c_loc];
      #pragma unroll
      for (int i=0;i<4;++i){
        int m_loc = wm*64 + s*16 + q*4 + i;
        float val = fmaxf(acc[s][tt][i] + bias, 0.f)*sc;
        unsigned hu = bfr(val);
        T[m_loc*128 + ((chunk ^ (m_loc&7))<<3) + cb] = (short)hu;
        acc[s][tt][i] = val - __uint_as_float(hu<<16);
      }
    }
  }
  __syncthreads();
  {
    int mrl = (lane>>2);
    int ccl = lane&3;
    #pragma unroll
    for (int e=0;e<8;++e){
      int hl = e&3, mg = e>>2;
      int m_loc = wave*32 + mg*16 + mrl;
      int cc16 = hl*4 + ccl;
      short8v v = *(const short8v*)(T + m_loc*128 + ((cc16 ^ (m_loc&7))<<3));
      *(short8v*)(Qbh + ((size_t)((n0>>5)+hl))*2097152 + (size_t)(m0+m_loc)*32 + ccl*8) = v;
    }
  }
  __syncthreads();
  #pragma unroll
  for (int s=0;s<4;++s){
    #pragma unroll
    for (int tt=0;tt<4;++tt){
      int c_loc = wn*64 + tt*16 + r;
      int chunk = c_loc >> 3, cb = c_loc & 7;
      #pragma unroll
      for (int i=0;i<4;++i){
        int m_loc = wm*64 + s*16 + q*4 + i;
        T[m_loc*128 + ((chunk ^ (m_loc&7))<<3) + cb] = (short)bfr(acc[s][tt][i]);
      }
    }
  }
  __syncthreads();
  {
    int mrl = (lane>>2);
    int ccl = lane&3;
    #pragma unroll
    for (int e=0;e<8;++e){
      int hl = e&3, mg = e>>2;
      int m_loc = wave*32 + mg*16 + mrl;
      int cc16 = hl*4 + ccl;
      short8v v = *(const short8v*)(T + m_loc*128 + ((cc16 ^ (m_loc&7))<<3));
      *(short8v*)(Qbl + ((size_t)((n0>>5)+hl))*2097152 + (size_t)(m0+m_loc)*32 + ccl*8) = v;
    }
  }
}

// ---- K/V proj MFMA: A = X planes (16384x256), B = ipw rows 256..767, N=512 ----
__global__ __launch_bounds__(256) void k_kvproj(const short* __restrict__ Xh, const short* __restrict__ Xl,
                                                const short* __restrict__ Wkh, const short* __restrict__ Wkl,
                                                const float* __restrict__ ipb, float* __restrict__ kb,
                                                float* __restrict__ vb){
  __shared__ __align__(16) short Ah[128*32];
  __shared__ __align__(16) short Al[128*32];
  __shared__ __align__(16) short Bh[128*32];
  __shared__ __align__(16) short Bl[128*32];
  int mblk = blockIdx.x >> 2, nblk = blockIdx.x & 3;
  int m0 = mblk*128, n0 = nblk*128;
  int t = threadIdx.x, wave = t>>6, lane = t&63;
  int wm = wave>>1, wn = wave&1;
  int q = lane>>4, r = lane&15;
  int cr = t>>2, cp = (t&3)*8;
  const f32x4 fz = {0.f,0.f,0.f,0.f};
  f32x4 acc[4][4];
  #pragma unroll
  for (int s=0;s<4;++s)
    #pragma unroll
    for (int tt=0;tt<4;++tt) acc[s][tt] = fz;
  for (int kc=0; kc<8; ++kc){
    int ko = kc*32;
    #pragma unroll
    for (int rep=0; rep<2; ++rep){
      int rr = cr + rep*64;
      int ga = (m0 + rr)*CD + ko + cp;
      *(short8v*)(Ah + rr*32 + cp) = *(const short8v*)(Xh + ga);
      *(short8v*)(Al + rr*32 + cp) = *(const short8v*)(Xl + ga);
      int gb = (n0 + rr)*CD + ko + cp;
      *(short8v*)(Bh + rr*32 + cp) = *(const short8v*)(Wkh + gb);
      *(short8v*)(Bl + rr*32 + cp) = *(const short8v*)(Wkl + gb);
    }
    __syncthreads();
    short8v ah[4], al[4];
    #pragma unroll
    for (int s=0;s<4;++s){
      int row = wm*64 + s*16 + r;
      ah[s] = *(const short8v*)(Ah + row*32 + q*8);
      al[s] = *(const short8v*)(Al + row*32 + q*8);
    }
    #pragma unroll
    for (int tt=0;tt<4;++tt){
      int brow = wn*64 + tt*16 + r;
      short8v bh = *(const short8v*)(Bh + brow*32 + q*8);
      short8v bl = *(const short8v*)(Bl + brow*32 + q*8);
      #pragma unroll
      for (int s=0;s<4;++s){
        acc[s][tt] = __builtin_amdgcn_mfma_f32_16x16x32_bf16(ah[s], bh, acc[s][tt], 0,0,0);
        acc[s][tt] = __builtin_amdgcn_mfma_f32_16x16x32_bf16(ah[s], bl, acc[s][tt], 0,0,0);
        acc[s][tt] = __builtin_amdgcn_mfma_f32_16x16x32_bf16(al[s], bh, acc[s][tt], 0,0,0);
      }
    }
    __syncthreads();
  }
  #pragma unroll
  for (int s=0;s<4;++s){
    #pragma unroll
    for (int tt=0;tt<4;++tt){
      int c = n0 + wn*64 + tt*16 + r;       // 0..511
      float bias = ipb[256 + c];
      #pragma unroll
      for (int i=0;i<4;++i){
        int m = m0 + wm*64 + s*16 + q*4 + i;
        float v = acc[s][tt][i] + bias;
        if (c < 256) kb[m*CD + c] = fmaxf(v, 0.f);
        else         vb[m*CD + (c-256)] = v;
      }
    }
  }
}

// ---- kv -> B planes for attn MFMA: B[bh][r][j], r = p*32+m (kv), 128+p (ksum), 132..143 zero ----
__global__ __launch_bounds__(256) void k_kv(const float* __restrict__ kb, const float* __restrict__ vbuf,
                                            const float* __restrict__ t2, short* __restrict__ Bhp,
                                            short* __restrict__ Blp){
  int bh = blockIdx.x; int b = bh >> 3, h = bh & 7;
  int t = threadIdx.x; int jq = t >> 5, m = t & 31;
  float acc[4][4];
  #pragma unroll
  for (int p=0;p<4;++p){ acc[p][0]=0.f; acc[p][1]=0.f; acc[p][2]=0.f; acc[p][3]=0.f; }
  const float* kbase = kb + h*HDIM + jq*4;
  const float* vbase = vbuf + h*HDIM + m;
  for (int n=0;n<256;++n){
    int ro = (b*NS + n)*CD;
    float4 k4 = *(const float4*)(kbase + ro);
    float vv = vbase[ro];
    float4 tt = *(const float4*)(t2 + n*4);
    float tv[4] = {tt.x, tt.y, tt.z, tt.w};
    float kk[4] = {k4.x, k4.y, k4.z, k4.w};
    #pragma unroll
    for (int p=0;p<4;++p){
      float tp = tv[p]*vv;
      #pragma unroll
      for (int jj=0;jj<4;++jj) acc[p][jj] += tp*kk[jj];
    }
  }
  short* bhb = Bhp + bh*4608;
  short* blb = Blp + bh*4608;
  #pragma unroll
  for (int p=0;p<4;++p){
    short4v h4, l4;
    #pragma unroll
    for (int jj=0;jj<4;++jj){ short a,bq; split2(acc[p][jj],a,bq); h4[jj]=a; l4[jj]=bq; }
    *(short4v*)(bhb + (p*32+m)*32 + jq*4) = h4;
    *(short4v*)(blb + (p*32+m)*32 + jq*4) = l4;
  }
  if (t < 128){
    int p = t >> 5, j = t & 31;
    float s=0.f;
    const float* kp = kb + h*HDIM + j;
    for (int n=0;n<256;++n) s += t2[n*4+p]*kp[(b*NS+n)*CD];
    short a,bq; split2(s,a,bq);
    bhb[(128+p)*32 + j] = a;
    blb[(128+p)*32 + j] = bq;
  } else {
    int idx = t - 128;       // zero pad rows 132..143 (384 shorts per plane)
    #pragma unroll
    for (int ii=0;ii<3;++ii){
      bhb[4224 + idx*3 + ii] = 0;
      blb[4224 + idx*3 + ii] = 0;
    }
  }
}

// ---- attn as MFMA GEMM per (b,h): A = Q head planes (M=1024,K=32), B = kv planes (N=144) ----
__global__ __launch_bounds__(256) void k_attn(const short* __restrict__ Qbh, const short* __restrict__ Qbl,
                                              const short* __restrict__ Bhg, const short* __restrict__ Blg,
                                              const float* __restrict__ t1,
                                              short* __restrict__ Ath, short* __restrict__ Atl){
  __shared__ __align__(16) short Bh[144*32];
  __shared__ __align__(16) short Bl[144*32];
  __shared__ __align__(16) short Ah[256*32];
  __shared__ __align__(16) short Al[256*32];
  int bh = blockIdx.x, b = bh>>3, h = bh&7;
  int t = threadIdx.x, lane = t&63, wave = t>>6;
  int q = lane>>4, r = lane&15;
  {
    const short8v* sh = (const short8v*)(Bhg + bh*4608);
    const short8v* sl = (const short8v*)(Blg + bh*4608);
    for (int i=t; i<576; i+=256){
      ((short8v*)Bh)[i] = sh[i];
      ((short8v*)Bl)[i] = sl[i];
    }
  }
  __syncthreads();
  short8v bf_h[9], bf_l[9];
  #pragma unroll
  for (int nt=0; nt<9; ++nt){
    int row = nt*16 + r;
    bf_h[nt] = *(const short8v*)(Bh + row*32 + q*8);
    bf_l[nt] = *(const short8v*)(Bl + row*32 + q*8);
  }
  const short* qh_base = Qbh + ((size_t)h*65536 + (size_t)b*1024)*32;
  const short* ql_base = Qbl + ((size_t)h*65536 + (size_t)b*1024)*32;
  const f32x4 fz = {0.f,0.f,0.f,0.f};
  for (int u=0; u<4; ++u){
    __syncthreads();
    {
      const short8v* sh = (const short8v*)(qh_base + (u*256 + t)*32);
      const short8v* sl = (const short8v*)(ql_base + (u*256 + t)*32);
      short8v* dh = (short8v*)(Ah + t*32);
      short8v* dl = (short8v*)(Al + t*32);
      #pragma unroll
      for (int i=0;i<4;++i){ dh[i]=sh[i]; dl[i]=sl[i]; }
    }
    __syncthreads();
    #pragma unroll
    for (int mi=0; mi<4; ++mi){
      int mt = wave*4 + mi;
      short8v ah = *(const short8v*)(Ah + (mt*16 + r)*32 + q*8);
      short8v al = *(const short8v*)(Al + (mt*16 + r)*32 + q*8);
      f32x4 acc[9];
      #pragma unroll
      for (int nt=0;nt<9;++nt) acc[nt]=fz;
      #pragma unroll
      for (int nt=0;nt<9;++nt){
        acc[nt] = __builtin_amdgcn_mfma_f32_16x16x32_bf16(ah, bf_h[nt], acc[nt],0,0,0);
        acc[nt] = __builtin_amdgcn_mfma_f32_16x16x32_bf16(ah, bf_l[nt], acc[nt],0,0,0);
        acc[nt] = __builtin_amdgcn_mfma_f32_16x16x32_bf16(al, bf_h[nt], acc[nt],0,0,0);
      }
      int nbase = u*256 + mt*16 + q*4;
      int src = lane & 48;
      #pragma unroll
      for (int i=0;i<4;++i){
        int n = nbase + i;
        float4 tv = *(const float4*)(t1 + n*4);
        float dp0 = __shfl(acc[8][i], src+0, 64);
        float dp1 = __shfl(acc[8][i], src+1, 64);
        float dp2 = __shfl(acc[8][i], src+2, 64);
        float dp3 = __shfl(acc[8][i], src+3, 64);
        float den = tv.x*dp0 + tv.y*dp1 + tv.z*dp2 + tv.w*dp3;
        float a0 = tv.x*acc[0][i] + tv.y*acc[2][i] + tv.z*acc[4][i] + tv.w*acc[6][i];
        float a1 = tv.x*acc[1][i] + tv.y*acc[3][i] + tv.z*acc[5][i] + tv.w*acc[7][i];
        float sgn = (den>0.f) ? 1.f : ((den<0.f)? -1.f : 0.f);
        float ad = fminf(fmaxf(fabsf(den), 1e-4f), 1e4f);
        float inv = (den != 0.f) ? 1.0f/(ad*sgn) : 0.f;
        float o0 = a0*inv, o1 = a1*inv;
        int mrow = b*NTOK + n;
        short h0,l0,h1,l1;
        split2(o0,h0,l0); split2(o1,h1,l1);
        Ath[mrow*CD + h*HDIM + r]      = h0;
        Atl[mrow*CD + h*HDIM + r]      = l0;
        Ath[mrow*CD + h*HDIM + 16 + r] = h1;
        Atl[mrow*CD + h*HDIM + 16 + r] = l1;
      }
    }
  }
}

// ---- out proj MFMA: A = At planes, B = ow planes; +bias, *se, transpose store ----
__global__ __launch_bounds__(256) void k_outproj(const short* __restrict__ Ath, const short* __restrict__ Atl,
                                                 const short* __restrict__ Woh, const short* __restrict__ Wol,
                                                 const float* __restrict__ obv, const float* __restrict__ se,
                                                 float* __restrict__ dout){
  __shared__ __align__(16) short Ah[128*32];
  __shared__ __align__(16) short Al[128*32];
  __shared__ __align__(16) short Bh[128*32];
  __shared__ __align__(16) short Bl[128*32];
  int mblk = blockIdx.x >> 1, nblk = blockIdx.x & 1;
  int m0 = mblk*128, n0 = nblk*128;
  int t = threadIdx.x, wave = t>>6, lane = t&63;
  int wm = wave>>1, wn = wave&1;
  int q = lane>>4, r = lane&15;
  int cr = t>>2, cp = (t&3)*8;
  const f32x4 fz = {0.f,0.f,0.f,0.f};
  f32x4 acc[4][4];
  #pragma unroll
  for (int s=0;s<4;++s)
    #pragma unroll
    for (int tt=0;tt<4;++tt) acc[s][tt] = fz;
  for (int kc=0; kc<8; ++kc){
    int ko = kc*32;
    #pragma unroll
    for (int rep=0; rep<2; ++rep){
      int rr = cr + rep*64;
      int ga = (m0 + rr)*CD + ko + cp;
      *(short8v*)(Ah + rr*32 + cp) = *(const short8v*)(Ath + ga);
      *(short8v*)(Al + rr*32 + cp) = *(const short8v*)(Atl + ga);
      int gb = (n0 + rr)*CD + ko + cp;
      *(short8v*)(Bh + rr*32 + cp) = *(const short8v*)(Woh + gb);
      *(short8v*)(Bl + rr*32 + cp) = *(const short8v*)(Wol + gb);
    }
    __syncthreads();
    short8v ah[4], al[4];
    #pragma unroll
    for (int s=0;s<4;++s){
      int row = wm*64 + s*16 + r;
      ah[s] = *(const short8v*)(Ah + row*32 + q*8);
      al[s] = *(const short8v*)(Al + row*32 + q*8);
    }
    #pragma unroll
    for (int tt=0;tt<4;++tt){
      int brow = wn*64 + tt*16 + r;
      short8v bh = *(const short8v*)(Bh + brow*32 + q*8);
      short8v bl = *(const short8v*)(Bl + brow*32 + q*8);
      #pragma unroll
      for (int s=0;s<4;++s){
        acc[s][tt] = __builtin_amdgcn_mfma_f32_16x16x32_bf16(ah[s], bh, acc[s][tt], 0,0,0);
        acc[s][tt] = __builtin_amdgcn_mfma_f32_16x16x32_bf16(ah[s], bl, acc[s][tt], 0,0,0);
        acc[s][tt] = __builtin_amdgcn_mfma_f32_16x16x32_bf16(al[s], bh, acc[s][tt], 0,0,0);
      }
    }
    __syncthreads();
  }
  #pragma unroll
  for (int s=0;s<4;++s){
    #pragma unroll
    for (int tt=0;tt<4;++tt){
      int c = n0 + wn*64 + tt*16 + r;
      float bias = obv[c];
      #pragma unroll
      for (int i=0;i<4;++i){
        int m = m0 + wm*64 + s*16 + q*4 + i;
        int bb = m >> 10, ntok = m & 1023;
        float sev = se[bb*CD + c];
        dout[(ntok*NB + bb)*CD + c] = (acc[s][tt][i] + bias)*sev;
      }
    }
  }
}

extern "C" void kernel_launch(void* const* d_in, const int* in_sizes, int n_in,
                              void* d_out, int out_size, void* d_ws, size_t ws_size,
                              hipStream_t stream) {
  const float* query = (const float*)d_in[0];
  const float* ipw = (const float*)d_in[5];
  const float* ipb = (const float*)d_in[6];
  const float* srw = (const float*)d_in[7];
  const float* srb = (const float*)d_in[8];
  const float* ng  = (const float*)d_in[9];
  const float* nbb = (const float*)d_in[10];
  const float* ow  = (const float*)d_in[11];
  const float* obv = (const float*)d_in[12];
  const float* sw1 = (const float*)d_in[13];
  const float* sw2 = (const float*)d_in[14];
  float* dout = (float*)d_out;
  float* ws = (float*)d_ws;

  // ---- workspace layout (float offsets) ----
  short* Qbh  = (short*)ws;                // 16.7M shorts: q head planes [h][m][32] [qproj -> attn]
  short* Qbl  = (short*)(ws + 8388608);
  float* R1   = ws + 16777216;             // 16,777,216 f  multi-use region
  float* kb   = R1;                        //  4,194,304 f  [kvproj -> k_kv]
  float* vb   = R1 + 4194304;              //  4,194,304 f  [kvproj -> k_kv]
  short* Ath  = (short*)R1;                //  At hi plane [attn -> outproj] (after kb/vb dead)
  short* Atl  = (short*)(R1 + 8388608);    //  At lo plane
  float* xr   = ws + 33554432;             //  4,194,304 f  [conv -> ln]
  short* Xh   = (short*)(ws + 37748736);   //  [ln -> kvproj]
  short* Xl   = (short*)(ws + 39845888);
  short* kvbh = (short*)(ws + 41943040);   //  512x144x32 shorts [k_kv -> attn]
  short* kvbl = (short*)(ws + 43122688);
  float* part = ws + 44302336;             //     65,536 f
  float* se   = ws + 44367872;             //     16,384 f
  float* t1   = ws + 44384256;             //      4,096 f
  float* t2   = ws + 44388352;             //      1,024 f
  short* Wih  = (short*)(ws + 44389376);   // 768x256
  short* Wil  = (short*)(ws + 44487680);
  short* Woh  = (short*)(ws + 44585984);   // 256x256
  short* Wol  = (short*)(ws + 44618752);
  short* Wsh  = (short*)(ws + 44651520);   // 256x1024
  short* Wsl  = (short*)(ws + 44782592);   // end: 44,913,664 f

  k_wcvt  <<<256,  256,0,stream>>>(ipw, ow, srw, Wih, Wil, Woh, Wol, Wsh, Wsl);
  k_trig  <<<4,    256,0,stream>>>(t1, t2);
  k_semean<<<256,  256,0,stream>>>(query, part);
  k_semlp <<<64,   256,0,stream>>>(part, sw1, sw2, se);
  k_conv  <<<512,  256,0,stream>>>(query, Wsh, Wsl, srb, xr);
  k_ln    <<<4096, 256,0,stream>>>(xr, ng, nbb, Xh, Xl);
  k_qproj <<<1024, 256,0,stream>>>(query, Wih, Wil, ipb, Qbh, Qbl);
  k_kvproj<<<512,  256,0,stream>>>(Xh, Xl, Wih + 256*CD, Wil + 256*CD, ipb, kb, vb);
  k_kv    <<<512,  256,0,stream>>>(kb, vb, t2, kvbh, kvbl);
  k_attn  <<<512,  256,0,stream>>>(Qbh, Qbl, kvbh, kvbl, t1, Ath, Atl);
  k_outproj<<<1024,256,0,stream>>>(Ath, Atl, Woh, Wol, obv, se, dout);
}

// Round 5
// 430.022 us; speedup vs baseline: 1.0828x; 1.0657x over previous
//
#include <hip/hip_runtime.h>

#define NTOK 1024
#define NB   64
#define CD   256
#define NHEAD 8
#define HDIM 32
#define NS 256
#define NBC 16384

typedef __attribute__((ext_vector_type(8))) short short8v;
typedef __attribute__((ext_vector_type(4))) short short4v;
typedef __attribute__((ext_vector_type(4))) float f32x4;

// round-to-nearest-even fp32 -> bf16 (low 16 bits returned)
__device__ __forceinline__ unsigned bfr(float x){
  unsigned u = __float_as_uint(x);
  return (u + 0x7fffu + ((u>>16)&1u)) >> 16;
}
// two-term split: x ~= hi + lo, both bf16
__device__ __forceinline__ void split2(float x, short &h, short &l){
  unsigned hu = bfr(x);
  float hf = __uint_as_float(hu << 16);
  unsigned lu = bfr(x - hf);
  h = (short)hu; l = (short)lu;
}

// ================= A: wcvt | trig | semean =================
__global__ __launch_bounds__(256) void k_pre(const float* __restrict__ ipw, const float* __restrict__ ow,
                                             const float* __restrict__ srw,
                                             short* __restrict__ Wih, short* __restrict__ Wil,
                                             short* __restrict__ Woh, short* __restrict__ Wol,
                                             short* __restrict__ Wsh, short* __restrict__ Wsl,
                                             float* __restrict__ t1, float* __restrict__ t2,
                                             const float* __restrict__ query, float* __restrict__ part){
  int bid = blockIdx.x, t = threadIdx.x;
  if (bid < 256){
    // ---- weights -> bf16 hi/lo planes ----
    int u = bid*256 + t;
    float xs[8];
    short* dh; short* dl; int dof;
    if (u < 24576){
      int n = u >> 5, off = (u & 31)*8;
      const float* s = ipw + n*CD + off;
      #pragma unroll
      for (int i=0;i<8;++i) xs[i] = s[i];
      dh = Wih; dl = Wil; dof = n*CD + off;
    } else if (u < 32768){
      int v = u - 24576;
      int n = v >> 5, off = (v & 31)*8;
      const float* s = ow + n*CD + off;
      #pragma unroll
      for (int i=0;i<8;++i) xs[i] = s[i];
      dh = Woh; dl = Wol; dof = n*CD + off;
    } else {
      int v = u - 32768;
      int n = v >> 7, koff = (v & 127)*8;
      int g = koff >> 8, cin0 = koff & 255;
      #pragma unroll
      for (int i=0;i<8;++i) xs[i] = srw[n*1024 + (cin0+i)*4 + g];
      dh = Wsh; dl = Wsl; dof = n*1024 + koff;
    }
    short8v h, l;
    #pragma unroll
    for (int i=0;i<8;++i){ short a,b; split2(xs[i],a,b); h[i]=a; l[i]=b; }
    *(short8v*)(dh + dof) = h;
    *(short8v*)(dl + dof) = l;
  } else if (bid < 260){
    // ---- trig tables ----
    int n = (bid-256)*256 + t;
    const float c = 1.57079632679489662f;
    float aa = c * (float)(n >> 5) / 32.0f;
    float bb = c * (float)(n & 31) / 32.0f;
    t1[n*4+0]=cosf(aa); t1[n*4+1]=sinf(aa); t1[n*4+2]=cosf(bb); t1[n*4+3]=sinf(bb);
    if (n < 256){
      float a2 = c * (float)(n >> 4) / 16.0f;
      float b2 = c * (float)(n & 15) / 16.0f;
      t2[n*4+0]=cosf(a2); t2[n*4+1]=sinf(a2); t2[n*4+2]=cosf(b2); t2[n*4+3]=sinf(b2);
    }
  } else {
    // ---- SE partial mean over tokens of raw fp32 query ----
    int vb_ = bid - 260;
    int b = vb_ >> 2, qr = vb_ & 3;
    const float* qp = query + (qr*256)*NBC + b*CD + t;
    float s0=0.f,s1=0.f,s2=0.f,s3=0.f;
    for (int n=0;n<256;n+=4){
      s0 += qp[(n  )*NBC];
      s1 += qp[(n+1)*NBC];
      s2 += qp[(n+2)*NBC];
      s3 += qp[(n+3)*NBC];
    }
    part[vb_*256 + t] = (s0+s1)+(s2+s3);
  }
}

// ================= B: conv | qproj | semlp =================
__global__ __launch_bounds__(256) void k_mid(const float* __restrict__ qf,
                                             const short* __restrict__ Wsh, const short* __restrict__ Wsl,
                                             const float* __restrict__ srb, float* __restrict__ xr,
                                             const short* __restrict__ Wih, const short* __restrict__ Wil,
                                             const float* __restrict__ ipb,
                                             short* __restrict__ Qbh, short* __restrict__ Qbl,
                                             const float* __restrict__ part, const float* __restrict__ w1,
                                             const float* __restrict__ w2, float* __restrict__ se){
  __shared__ __align__(16) short smem[16384];   // 32KB
  int bid = blockIdx.x, t = threadIdx.x;
  if (bid < 512){
    // ---- conv 2x2/s2 as MFMA GEMM: tile 64m x 128n, K'=1024; A from fp32 query + split2 ----
    short* Ah = smem;
    short* Al = smem + 2048;
    short* Bh = smem + 4096;
    short* Bl = smem + 8192;
    int mblk = bid >> 1, nblk = bid & 1;
    int m0 = mblk*64, n0 = nblk*128;
    int b = mblk >> 2;
    int pos0 = m0 & 255;
    int wave = t>>6, lane = t&63;
    int wm = wave>>1, wn = wave&1;
    int q = lane>>4, r = lane&15;
    int ra = t>>2, pa = (t&3)*8;
    int posA = pos0 + ra, hs = posA>>4, ws2 = posA&15;
    const f32x4 fz = {0.f,0.f,0.f,0.f};
    f32x4 acc[2][4];
    #pragma unroll
    for (int s=0;s<2;++s)
      #pragma unroll
      for (int tt=0;tt<4;++tt) acc[s][tt] = fz;
    for (int kc=0; kc<32; ++kc){
      int g = kc>>3, cin0 = (kc&7)*32;
      int gh = g>>1, gw = g&1;
      int tok = (2*hs+gh)*32 + 2*ws2 + gw;
      const float* src = qf + (size_t)tok*NBC + b*CD + cin0 + pa;
      float4 fa = *(const float4*)src;
      float4 fb = *(const float4*)(src+4);
      float xs[8] = {fa.x,fa.y,fa.z,fa.w,fb.x,fb.y,fb.z,fb.w};
      short8v hh, ll;
      #pragma unroll
      for (int i=0;i<8;++i){ short a0,b0; split2(xs[i],a0,b0); hh[i]=a0; ll[i]=b0; }
      *(short8v*)(Ah + ra*32 + pa) = hh;
      *(short8v*)(Al + ra*32 + pa) = ll;
      int ko = kc*32;
      #pragma unroll
      for (int rep=0; rep<2; ++rep){
        int rr = ra + rep*64;
        int gb = (n0 + rr)*1024 + ko + pa;
        *(short8v*)(Bh + rr*32 + pa) = *(const short8v*)(Wsh + gb);
        *(short8v*)(Bl + rr*32 + pa) = *(const short8v*)(Wsl + gb);
      }
      __syncthreads();
      short8v ah[2], al[2];
      #pragma unroll
      for (int s=0;s<2;++s){
        int row = wm*32 + s*16 + r;
        ah[s] = *(const short8v*)(Ah + row*32 + q*8);
        al[s] = *(const short8v*)(Al + row*32 + q*8);
      }
      #pragma unroll
      for (int tt=0;tt<4;++tt){
        int brow = wn*64 + tt*16 + r;
        short8v bh = *(const short8v*)(Bh + brow*32 + q*8);
        short8v bl = *(const short8v*)(Bl + brow*32 + q*8);
        #pragma unroll
        for (int s=0;s<2;++s){
          acc[s][tt] = __builtin_amdgcn_mfma_f32_16x16x32_bf16(ah[s], bh, acc[s][tt], 0,0,0);
          acc[s][tt] = __builtin_amdgcn_mfma_f32_16x16x32_bf16(ah[s], bl, acc[s][tt], 0,0,0);
          acc[s][tt] = __builtin_amdgcn_mfma_f32_16x16x32_bf16(al[s], bh, acc[s][tt], 0,0,0);
        }
      }
      __syncthreads();
    }
    #pragma unroll
    for (int s=0;s<2;++s){
      #pragma unroll
      for (int tt=0;tt<4;++tt){
        int c = n0 + wn*64 + tt*16 + r;
        float bias = srb[c];
        #pragma unroll
        for (int i=0;i<4;++i){
          int m = m0 + wm*32 + s*16 + q*4 + i;
          xr[m*CD + c] = acc[s][tt][i] + bias;
        }
      }
    }
  } else if (bid < 1536){
    // ---- Q proj MFMA: 128x128 tile; A from fp32 query + split2; swizzled staging;
    //      epilogue: relu,*sc,split2 -> LDS transpose -> head-major stores [h][m][32] ----
    short* Ah = smem;
    short* Al = smem + 4096;
    short* Bh = smem + 8192;
    short* Bl = smem + 12288;
    int qb_ = bid - 512;
    int mblk = qb_ >> 1, nblk = qb_ & 1;
    int m0 = mblk*128, n0 = nblk*128;
    int wave = t>>6, lane = t&63;
    int wm = wave>>1, wn = wave&1;
    int q = lane>>4, r = lane&15;
    int cr = t>>2, cp = (t&3)*8;
    int cpS = (((t&3) ^ ((cr>>1)&3)))*8;       // swizzled staging-write chunk
    int sw8 = ((r>>1)&3)*8;                    // lane-constant fragment-read swizzle
    const f32x4 fz = {0.f,0.f,0.f,0.f};
    f32x4 acc[4][4];
    #pragma unroll
    for (int s=0;s<4;++s)
      #pragma unroll
      for (int tt=0;tt<4;++tt) acc[s][tt] = fz;
    for (int kc=0; kc<8; ++kc){
      int ko = kc*32;
      #pragma unroll
      for (int rep=0; rep<2; ++rep){
        int rr = cr + rep*64;
        int m = m0 + rr;
        const float* src = qf + (size_t)(m & 1023)*NBC + (m >> 10)*CD + ko + cp;
        float4 fa = *(const float4*)src;
        float4 fb = *(const float4*)(src+4);
        float xs[8] = {fa.x,fa.y,fa.z,fa.w,fb.x,fb.y,fb.z,fb.w};
        short8v hh, ll;
        #pragma unroll
        for (int i=0;i<8;++i){ short a0,b0; split2(xs[i],a0,b0); hh[i]=a0; ll[i]=b0; }
        *(short8v*)(Ah + rr*32 + cpS) = hh;
        *(short8v*)(Al + rr*32 + cpS) = ll;
        int gb = (n0 + rr)*CD + ko + cp;
        *(short8v*)(Bh + rr*32 + cpS) = *(const short8v*)(Wih + gb);
        *(short8v*)(Bl + rr*32 + cpS) = *(const short8v*)(Wil + gb);
      }
      __syncthreads();
      short8v ah[4], al[4];
      #pragma unroll
      for (int s=0;s<4;++s){
        int row = wm*64 + s*16 + r;
        ah[s] = *(const short8v*)(Ah + row*32 + ((q*8)^sw8));
        al[s] = *(const short8v*)(Al + row*32 + ((q*8)^sw8));
      }
      #pragma unroll
      for (int tt=0;tt<4;++tt){
        int brow = wn*64 + tt*16 + r;
        short8v bh = *(const short8v*)(Bh + brow*32 + ((q*8)^sw8));
        short8v bl = *(const short8v*)(Bl + brow*32 + ((q*8)^sw8));
        #pragma unroll
        for (int s=0;s<4;++s){
          acc[s][tt] = __builtin_amdgcn_mfma_f32_16x16x32_bf16(ah[s], bh, acc[s][tt], 0,0,0);
          acc[s][tt] = __builtin_amdgcn_mfma_f32_16x16x32_bf16(ah[s], bl, acc[s][tt], 0,0,0);
          acc[s][tt] = __builtin_amdgcn_mfma_f32_16x16x32_bf16(al[s], bh, acc[s][tt], 0,0,0);
        }
      }
      __syncthreads();
    }
    const float sc = 0.17677669529663687f;
    short* T = smem;   // 128 rows x 128 shorts
    #pragma unroll
    for (int s=0;s<4;++s){
      #pragma unroll
      for (int tt=0;tt<4;++tt){
        int c_loc = wn*64 + tt*16 + r;
        int chunk = c_loc >> 3, cb = c_loc & 7;
        float bias = ipb[n0 + c_loc];
        #pragma unroll
        for (int i=0;i<4;++i){
          int m_loc = wm*64 + s*16 + q*4 + i;
          float val = fmaxf(acc[s][tt][i] + bias, 0.f)*sc;
          unsigned hu = bfr(val);
          T[m_loc*128 + ((chunk ^ (m_loc&7))<<3) + cb] = (short)hu;
          acc[s][tt][i] = val - __uint_as_float(hu<<16);
        }
      }
    }
    __syncthreads();
    {
      int mrl = (lane>>2);
      int ccl = lane&3;
      #pragma unroll
      for (int e=0;e<8;++e){
        int hl = e&3, mg = e>>2;
        int m_loc = wave*32 + mg*16 + mrl;
        int cc16 = hl*4 + ccl;
        short8v v = *(const short8v*)(T + m_loc*128 + ((cc16 ^ (m_loc&7))<<3));
        *(short8v*)(Qbh + ((size_t)((n0>>5)+hl))*2097152 + (size_t)(m0+m_loc)*32 + ccl*8) = v;
      }
    }
    __syncthreads();
    #pragma unroll
    for (int s=0;s<4;++s){
      #pragma unroll
      for (int tt=0;tt<4;++tt){
        int c_loc = wn*64 + tt*16 + r;
        int chunk = c_loc >> 3, cb = c_loc & 7;
        #pragma unroll
        for (int i=0;i<4;++i){
          int m_loc = wm*64 + s*16 + q*4 + i;
          T[m_loc*128 + ((chunk ^ (m_loc&7))<<3) + cb] = (short)bfr(acc[s][tt][i]);
        }
      }
    }
    __syncthreads();
    {
      int mrl = (lane>>2);
      int ccl = lane&3;
      #pragma unroll
      for (int e=0;e<8;++e){
        int hl = e&3, mg = e>>2;
        int m_loc = wave*32 + mg*16 + mrl;
        int cc16 = hl*4 + ccl;
        short8v v = *(const short8v*)(T + m_loc*128 + ((cc16 ^ (m_loc&7))<<3));
        *(short8v*)(Qbl + ((size_t)((n0>>5)+hl))*2097152 + (size_t)(m0+m_loc)*32 + ccl*8) = v;
      }
    }
  } else {
    // ---- SE MLP ----
    float* sm = (float*)smem;
    float* s1s = sm + 256;
    int b = bid - 1536;
    float s = (part[(b*4+0)*256+t]+part[(b*4+1)*256+t])+(part[(b*4+2)*256+t]+part[(b*4+3)*256+t]);
    sm[t] = s*(1.0f/1024.0f);
    __syncthreads();
    if (t < 128){
      float a = 0.f;
      const float* wr = w1 + t*256;
      for (int c=0;c<256;c+=4){
        float4 wf = *(const float4*)(wr+c);
        a += sm[c]*wf.x + sm[c+1]*wf.y + sm[c+2]*wf.z + sm[c+3]*wf.w;
      }
      s1s[t] = fmaxf(a, 0.f);
    }
    __syncthreads();
    float a = 0.f;
    const float* wr2 = w2 + t*128;
    for (int c=0;c<128;c+=4){
      float4 wf = *(const float4*)(wr2+c);
      a += s1s[c]*wf.x + s1s[c+1]*wf.y + s1s[c+2]*wf.z + s1s[c+3]*wf.w;
    }
    se[b*256+t] = 1.0f/(1.0f+expf(-a));
  }
}

// ---- layernorm over C; reads xr fp32, writes bf16 hi/lo planes ----
__global__ __launch_bounds__(256) void k_ln(const float* __restrict__ xr, const float* __restrict__ g,
                                            const float* __restrict__ bta, short* __restrict__ Xh,
                                            short* __restrict__ Xl){
  int wv = threadIdx.x >> 6, lane = threadIdx.x & 63;
  int row = blockIdx.x*4 + wv;
  float4 v = ((const float4*)(xr + row*CD))[lane];
  float s = (v.x+v.y)+(v.z+v.w);
  #pragma unroll
  for (int off=1; off<64; off<<=1) s += __shfl_xor(s, off, 64);
  float mu = s * (1.0f/256.0f);
  float dx=v.x-mu, dy=v.y-mu, dz=v.z-mu, dw=v.w-mu;
  float s2 = (dx*dx+dy*dy)+(dz*dz+dw*dw);
  #pragma unroll
  for (int off=1; off<64; off<<=1) s2 += __shfl_xor(s2, off, 64);
  float inv = 1.0f / sqrtf(s2*(1.0f/256.0f) + 1e-5f);
  float4 gr = ((const float4*)g)[lane];
  float4 br = ((const float4*)bta)[lane];
  float o0 = dx*inv*gr.x + br.x;
  float o1 = dy*inv*gr.y + br.y;
  float o2 = dz*inv*gr.z + br.z;
  float o3 = dw*inv*gr.w + br.w;
  short4v h, l; short a0,b0;
  split2(o0,a0,b0); h[0]=a0; l[0]=b0;
  split2(o1,a0,b0); h[1]=a0; l[1]=b0;
  split2(o2,a0,b0); h[2]=a0; l[2]=b0;
  split2(o3,a0,b0); h[3]=a0; l[3]=b0;
  *(short4v*)(Xh + row*CD + lane*4) = h;
  *(short4v*)(Xl + row*CD + lane*4) = l;
}

// ---- K/V proj MFMA: A = X planes (16384x256), B = ipw rows 256..767, N=512 ----
__global__ __launch_bounds__(256) void k_kvproj(const short* __restrict__ Xh, const short* __restrict__ Xl,
                                                const short* __restrict__ Wkh, const short* __restrict__ Wkl,
                                                const float* __restrict__ ipb, float* __restrict__ kb,
                                                float* __restrict__ vb){
  __shared__ __align__(16) short Ah[128*32];
  __shared__ __align__(16) short Al[128*32];
  __shared__ __align__(16) short Bh[128*32];
  __shared__ __align__(16) short Bl[128*32];
  int mblk = blockIdx.x >> 2, nblk = blockIdx.x & 3;
  int m0 = mblk*128, n0 = nblk*128;
  int t = threadIdx.x, wave = t>>6, lane = t&63;
  int wm = wave>>1, wn = wave&1;
  int q = lane>>4, r = lane&15;
  int cr = t>>2, cp = (t&3)*8;
  const f32x4 fz = {0.f,0.f,0.f,0.f};
  f32x4 acc[4][4];
  #pragma unroll
  for (int s=0;s<4;++s)
    #pragma unroll
    for (int tt=0;tt<4;++tt) acc[s][tt] = fz;
  for (int kc=0; kc<8; ++kc){
    int ko = kc*32;
    #pragma unroll
    for (int rep=0; rep<2; ++rep){
      int rr = cr + rep*64;
      int ga = (m0 + rr)*CD + ko + cp;
      *(short8v*)(Ah + rr*32 + cp) = *(const short8v*)(Xh + ga);
      *(short8v*)(Al + rr*32 + cp) = *(const short8v*)(Xl + ga);
      int gb = (n0 + rr)*CD + ko + cp;
      *(short8v*)(Bh + rr*32 + cp) = *(const short8v*)(Wkh + gb);
      *(short8v*)(Bl + rr*32 + cp) = *(const short8v*)(Wkl + gb);
    }
    __syncthreads();
    short8v ah[4], al[4];
    #pragma unroll
    for (int s=0;s<4;++s){
      int row = wm*64 + s*16 + r;
      ah[s] = *(const short8v*)(Ah + row*32 + q*8);
      al[s] = *(const short8v*)(Al + row*32 + q*8);
    }
    #pragma unroll
    for (int tt=0;tt<4;++tt){
      int brow = wn*64 + tt*16 + r;
      short8v bh = *(const short8v*)(Bh + brow*32 + q*8);
      short8v bl = *(const short8v*)(Bl + brow*32 + q*8);
      #pragma unroll
      for (int s=0;s<4;++s){
        acc[s][tt] = __builtin_amdgcn_mfma_f32_16x16x32_bf16(ah[s], bh, acc[s][tt], 0,0,0);
        acc[s][tt] = __builtin_amdgcn_mfma_f32_16x16x32_bf16(ah[s], bl, acc[s][tt], 0,0,0);
        acc[s][tt] = __builtin_amdgcn_mfma_f32_16x16x32_bf16(al[s], bh, acc[s][tt], 0,0,0);
      }
    }
    __syncthreads();
  }
  #pragma unroll
  for (int s=0;s<4;++s){
    #pragma unroll
    for (int tt=0;tt<4;++tt){
      int c = n0 + wn*64 + tt*16 + r;       // 0..511
      float bias = ipb[256 + c];
      #pragma unroll
      for (int i=0;i<4;++i){
        int m = m0 + wm*64 + s*16 + q*4 + i;
        float v = acc[s][tt][i] + bias;
        if (c < 256) kb[m*CD + c] = fmaxf(v, 0.f);
        else         vb[m*CD + (c-256)] = v;
      }
    }
  }
}

// ================= E: kv + attn fused per (b,h); kv planes built in LDS =================
__global__ __launch_bounds__(256) void k_kvattn(const float* __restrict__ kb, const float* __restrict__ vbuf,
                                                const float* __restrict__ t2,
                                                const short* __restrict__ Qbh, const short* __restrict__ Qbl,
                                                const float* __restrict__ t1,
                                                short* __restrict__ Ath, short* __restrict__ Atl){
  __shared__ __align__(16) short Bh[144*32];
  __shared__ __align__(16) short Bl[144*32];
  __shared__ __align__(16) short Ah[256*32];
  __shared__ __align__(16) short Al[256*32];
  int bh = blockIdx.x, b = bh>>3, h = bh&7;
  int t = threadIdx.x, lane = t&63, wave = t>>6;
  int q = lane>>4, r = lane&15;
  // ---- phase 1: kv (t2-weighted K^T V outer products) straight into LDS B-planes ----
  {
    int jq = t >> 5, m = t & 31;
    float acc[4][4];
    #pragma unroll
    for (int p=0;p<4;++p){ acc[p][0]=0.f; acc[p][1]=0.f; acc[p][2]=0.f; acc[p][3]=0.f; }
    const float* kbase = kb + h*HDIM + jq*4;
    const float* vbase = vbuf + h*HDIM + m;
    for (int n=0;n<256;++n){
      int ro = (b*NS + n)*CD;
      float4 k4 = *(const float4*)(kbase + ro);
      float vv = vbase[ro];
      float4 tt = *(const float4*)(t2 + n*4);
      float tv[4] = {tt.x, tt.y, tt.z, tt.w};
      float kk[4] = {k4.x, k4.y, k4.z, k4.w};
      #pragma unroll
      for (int p=0;p<4;++p){
        float tp = tv[p]*vv;
        #pragma unroll
        for (int jj=0;jj<4;++jj) acc[p][jj] += tp*kk[jj];
      }
    }
    #pragma unroll
    for (int p=0;p<4;++p){
      short4v h4, l4;
      #pragma unroll
      for (int jj=0;jj<4;++jj){ short a,bq; split2(acc[p][jj],a,bq); h4[jj]=a; l4[jj]=bq; }
      *(short4v*)(Bh + (p*32+m)*32 + jq*4) = h4;
      *(short4v*)(Bl + (p*32+m)*32 + jq*4) = l4;
    }
    if (t < 128){
      int p = t >> 5, j = t & 31;
      float s=0.f;
      const float* kp = kb + h*HDIM + j;
      for (int n=0;n<256;++n) s += t2[n*4+p]*kp[(b*NS+n)*CD];
      short a,bq; split2(s,a,bq);
      Bh[(128+p)*32 + j] = a;
      Bl[(128+p)*32 + j] = bq;
    } else {
      int idx = t - 128;       // zero pad rows 132..143 (384 shorts per plane)
      #pragma unroll
      for (int ii=0;ii<3;++ii){
        Bh[4224 + idx*3 + ii] = 0;
        Bl[4224 + idx*3 + ii] = 0;
      }
    }
  }
  __syncthreads();
  // ---- phase 2: attn GEMM (A = Q head planes, B = LDS planes) ----
  short8v bf_h[9], bf_l[9];
  #pragma unroll
  for (int nt=0; nt<9; ++nt){
    int row = nt*16 + r;
    bf_h[nt] = *(const short8v*)(Bh + row*32 + q*8);
    bf_l[nt] = *(const short8v*)(Bl + row*32 + q*8);
  }
  const short* qh_base = Qbh + ((size_t)h*65536 + (size_t)b*1024)*32;
  const short* ql_base = Qbl + ((size_t)h*65536 + (size_t)b*1024)*32;
  const f32x4 fz = {0.f,0.f,0.f,0.f};
  for (int u=0; u<4; ++u){
    __syncthreads();
    {
      const short8v* sh = (const short8v*)(qh_base + (u*256 + t)*32);
      const short8v* sl = (const short8v*)(ql_base + (u*256 + t)*32);
      short8v* dh = (short8v*)(Ah + t*32);
      short8v* dl = (short8v*)(Al + t*32);
      #pragma unroll
      for (int i=0;i<4;++i){ dh[i]=sh[i]; dl[i]=sl[i]; }
    }
    __syncthreads();
    #pragma unroll
    for (int mi=0; mi<4; ++mi){
      int mt = wave*4 + mi;
      short8v ah = *(const short8v*)(Ah + (mt*16 + r)*32 + q*8);
      short8v al = *(const short8v*)(Al + (mt*16 + r)*32 + q*8);
      f32x4 acc[9];
      #pragma unroll
      for (int nt=0;nt<9;++nt) acc[nt]=fz;
      #pragma unroll
      for (int nt=0;nt<9;++nt){
        acc[nt] = __builtin_amdgcn_mfma_f32_16x16x32_bf16(ah, bf_h[nt], acc[nt],0,0,0);
        acc[nt] = __builtin_amdgcn_mfma_f32_16x16x32_bf16(ah, bf_l[nt], acc[nt],0,0,0);
        acc[nt] = __builtin_amdgcn_mfma_f32_16x16x32_bf16(al, bf_h[nt], acc[nt],0,0,0);
      }
      int nbase = u*256 + mt*16 + q*4;
      int src = lane & 48;
      #pragma unroll
      for (int i=0;i<4;++i){
        int n = nbase + i;
        float4 tv = *(const float4*)(t1 + n*4);
        float dp0 = __shfl(acc[8][i], src+0, 64);
        float dp1 = __shfl(acc[8][i], src+1, 64);
        float dp2 = __shfl(acc[8][i], src+2, 64);
        float dp3 = __shfl(acc[8][i], src+3, 64);
        float den = tv.x*dp0 + tv.y*dp1 + tv.z*dp2 + tv.w*dp3;
        float a0 = tv.x*acc[0][i] + tv.y*acc[2][i] + tv.z*acc[4][i] + tv.w*acc[6][i];
        float a1 = tv.x*acc[1][i] + tv.y*acc[3][i] + tv.z*acc[5][i] + tv.w*acc[7][i];
        float sgn = (den>0.f) ? 1.f : ((den<0.f)? -1.f : 0.f);
        float ad = fminf(fmaxf(fabsf(den), 1e-4f), 1e4f);
        float inv = (den != 0.f) ? 1.0f/(ad*sgn) : 0.f;
        float o0 = a0*inv, o1 = a1*inv;
        int mrow = b*NTOK + n;
        short h0,l0,h1,l1;
        split2(o0,h0,l0); split2(o1,h1,l1);
        Ath[mrow*CD + h*HDIM + r]      = h0;
        Atl[mrow*CD + h*HDIM + r]      = l0;
        Ath[mrow*CD + h*HDIM + 16 + r] = h1;
        Atl[mrow*CD + h*HDIM + 16 + r] = l1;
      }
    }
  }
}

// ---- out proj MFMA: A = At planes, B = ow planes; +bias, *se, transpose store ----
__global__ __launch_bounds__(256) void k_outproj(const short* __restrict__ Ath, const short* __restrict__ Atl,
                                                 const short* __restrict__ Woh, const short* __restrict__ Wol,
                                                 const float* __restrict__ obv, const float* __restrict__ se,
                                                 float* __restrict__ dout){
  __shared__ __align__(16) short Ah[128*32];
  __shared__ __align__(16) short Al[128*32];
  __shared__ __align__(16) short Bh[128*32];
  __shared__ __align__(16) short Bl[128*32];
  int mblk = blockIdx.x >> 1, nblk = blockIdx.x & 1;
  int m0 = mblk*128, n0 = nblk*128;
  int t = threadIdx.x, wave = t>>6, lane = t&63;
  int wm = wave>>1, wn = wave&1;
  int q = lane>>4, r = lane&15;
  int cr = t>>2, cp = (t&3)*8;
  const f32x4 fz = {0.f,0.f,0.f,0.f};
  f32x4 acc[4][4];
  #pragma unroll
  for (int s=0;s<4;++s)
    #pragma unroll
    for (int tt=0;tt<4;++tt) acc[s][tt] = fz;
  for (int kc=0; kc<8; ++kc){
    int ko = kc*32;
    #pragma unroll
    for (int rep=0; rep<2; ++rep){
      int rr = cr + rep*64;
      int ga = (m0 + rr)*CD + ko + cp;
      *(short8v*)(Ah + rr*32 + cp) = *(const short8v*)(Ath + ga);
      *(short8v*)(Al + rr*32 + cp) = *(const short8v*)(Atl + ga);
      int gb = (n0 + rr)*CD + ko + cp;
      *(short8v*)(Bh + rr*32 + cp) = *(const short8v*)(Woh + gb);
      *(short8v*)(Bl + rr*32 + cp) = *(const short8v*)(Wol + gb);
    }
    __syncthreads();
    short8v ah[4], al[4];
    #pragma unroll
    for (int s=0;s<4;++s){
      int row = wm*64 + s*16 + r;
      ah[s] = *(const short8v*)(Ah + row*32 + q*8);
      al[s] = *(const short8v*)(Al + row*32 + q*8);
    }
    #pragma unroll
    for (int tt=0;tt<4;++tt){
      int brow = wn*64 + tt*16 + r;
      short8v bh = *(const short8v*)(Bh + brow*32 + q*8);
      short8v bl = *(const short8v*)(Bl + brow*32 + q*8);
      #pragma unroll
      for (int s=0;s<4;++s){
        acc[s][tt] = __builtin_amdgcn_mfma_f32_16x16x32_bf16(ah[s], bh, acc[s][tt], 0,0,0);
        acc[s][tt] = __builtin_amdgcn_mfma_f32_16x16x32_bf16(ah[s], bl, acc[s][tt], 0,0,0);
        acc[s][tt] = __builtin_amdgcn_mfma_f32_16x16x32_bf16(al[s], bh, acc[s][tt], 0,0,0);
      }
    }
    __syncthreads();
  }
  #pragma unroll
  for (int s=0;s<4;++s){
    #pragma unroll
    for (int tt=0;tt<4;++tt){
      int c = n0 + wn*64 + tt*16 + r;
      float bias = obv[c];
      #pragma unroll
      for (int i=0;i<4;++i){
        int m = m0 + wm*64 + s*16 + q*4 + i;
        int bb = m >> 10, ntok = m & 1023;
        float sev = se[bb*CD + c];
        dout[(ntok*NB + bb)*CD + c] = (acc[s][tt][i] + bias)*sev;
      }
    }
  }
}

extern "C" void kernel_launch(void* const* d_in, const int* in_sizes, int n_in,
                              void* d_out, int out_size, void* d_ws, size_t ws_size,
                              hipStream_t stream) {
  const float* query = (const float*)d_in[0];
  const float* ipw = (const float*)d_in[5];
  const float* ipb = (const float*)d_in[6];
  const float* srw = (const float*)d_in[7];
  const float* srb = (const float*)d_in[8];
  const float* ng  = (const float*)d_in[9];
  const float* nbb = (const float*)d_in[10];
  const float* ow  = (const float*)d_in[11];
  const float* obv = (const float*)d_in[12];
  const float* sw1 = (const float*)d_in[13];
  const float* sw2 = (const float*)d_in[14];
  float* dout = (float*)d_out;
  float* ws = (float*)d_ws;

  // ---- workspace layout (float offsets) ----
  short* Qbh  = (short*)ws;                // q head planes [h][m][32] [qproj -> kvattn]
  short* Qbl  = (short*)(ws + 8388608);
  float* R1   = ws + 16777216;             // multi-use region (16,777,216 f)
  float* kb   = R1;                        //  4,194,304 f  [kvproj -> kvattn]
  float* vb   = R1 + 4194304;              //  4,194,304 f  [kvproj -> kvattn]
  short* Ath  = (short*)(R1 + 8388608);    //  At hi plane [kvattn -> outproj] (R1 upper half, no overlap with kb/vb)
  short* Atl  = (short*)(ws + 33554432);   //  At lo plane (over xr/Xh/Xl, dead by kvattn)
  float* xr   = ws + 33554432;             //  4,194,304 f  [conv -> ln]   (overlaid by Atl later)
  short* Xh   = (short*)(ws + 37748736);   //  [ln -> kvproj]
  short* Xl   = (short*)(ws + 39845888);
  float* part = ws + 44302336;             //     65,536 f
  float* se   = ws + 44367872;             //     16,384 f
  float* t1   = ws + 44384256;             //      4,096 f
  float* t2   = ws + 44388352;             //      1,024 f
  short* Wih  = (short*)(ws + 44389376);   // 768x256
  short* Wil  = (short*)(ws + 44487680);
  short* Woh  = (short*)(ws + 44585984);   // 256x256
  short* Wol  = (short*)(ws + 44618752);
  short* Wsh  = (short*)(ws + 44651520);   // 256x1024
  short* Wsl  = (short*)(ws + 44782592);   // end: 44,913,664 f

  // A: wcvt(256) | trig(4) | semean(256)
  k_pre   <<<516,  256,0,stream>>>(ipw, ow, srw, Wih, Wil, Woh, Wol, Wsh, Wsl, t1, t2, query, part);
  // B: conv(512) | qproj(1024) | semlp(64)
  k_mid   <<<1600, 256,0,stream>>>(query, Wsh, Wsl, srb, xr, Wih, Wil, ipb, Qbh, Qbl, part, sw1, sw2, se);
  // C
  k_ln    <<<4096, 256,0,stream>>>(xr, ng, nbb, Xh, Xl);
  // D
  k_kvproj<<<512,  256,0,stream>>>(Xh, Xl, Wih + 256*CD, Wil + 256*CD, ipb, kb, vb);
  // E: kv + attn fused (kv planes never leave LDS)
  k_kvattn<<<512,  256,0,stream>>>(kb, vb, t2, Qbh, Qbl, t1, Ath, Atl);
  // F
  k_outproj<<<1024,256,0,stream>>>(Ath, Atl, Woh, Wol, obv, se, dout);
}